// Round 11
// baseline (1459.338 us; speedup 1.0000x reference)
//
#include <hip/hip_runtime.h>

// DKVMN forward, round 25 — kM occupancy fix (512 -> 1024 threads).
// R24 green: kS 920 us (EPSW 1e-6 confirmed safe, absmax 0.0039), total 1446.
// kM (~430 us by subtraction) shows Occupancy 15.7% / VALUBusy 15.6%: 512 thr
// + 140 KB LDS = 1 block/CU = 2 waves/SIMD -> latency-bound with nothing to
// hide LDS/L2 latency. R25: kM runs 1024 threads (16 waves x 4 p-rows instead
// of 8 x 8) -> 4 waves/SIMD at the same LDS footprint; identical arithmetic
// sequence per (p,j) so output is bit-identical. kS/kW/kG byte-identical to
// R24. Banned: fdot2/bit_cast (R21/R22 deterministic miscompute).
//   kW: wtab[513][512] fp32   kG: etab/atab[1025][256] fp32   (3.2 MB, hot)
//   kS: 512 blocks x 1024 thr; named m0..m15; unroll-1 j-loop; tid<256
//       float4 unroll-4 drain; GRP4 skip EPSW=1e-6.
//   kM: 2048 blocks x 1024 thr; s_f fp32, s_W1 fp16 (dot4 fma), s_h1.
// ws = 3.2 MB + 128 MiB.

#define B_ 256
#define T_ 512
#define N_ 512
#define DK_ 64
#define DV_ 256
#define S_ 64
#define NP_ (B_ * T_)
#define NCID 513
#define NIID 1025
#define TB_ 16
#define EPSW 1e-6f

typedef _Float16 h16;
typedef __attribute__((ext_vector_type(4))) _Float16 half4;

__device__ __forceinline__ float dot4(float4 a, float4 b) {
  return a.x * b.x + a.y * b.y + a.z * b.z + a.w * b.w;
}
__device__ __forceinline__ float4 h2f(half4 h) {
  return make_float4((float)h.x, (float)h.y, (float)h.z, (float)h.w);
}
__device__ __forceinline__ half4 f2h(float4 f) {
  half4 h;
  h.x = (h16)f.x; h.y = (h16)f.y; h.z = (h16)f.z; h.w = (h16)f.w;
  return h;
}

// ============ kW: wtab[c][n] = softmax_n(q_c . K_n), 513 blocks ============
__global__ __launch_bounds__(512) void kW(const float* __restrict__ Kmem,
                                          const float* __restrict__ cemb,
                                          float* __restrict__ wtab) {
  __shared__ float s_q[DK_];
  __shared__ float s_red[16];
  const int tid = threadIdx.x, c = blockIdx.x;
  if (tid < DK_) s_q[tid] = c ? cemb[c * DK_ + tid] : 0.f;
  __syncthreads();
  const int n = tid;
  const float4* kr = (const float4*)(Kmem + n * DK_);
  float acc = 0.f;
#pragma unroll
  for (int kk = 0; kk < DK_ / 4; ++kk) acc += dot4(kr[kk], *(const float4*)&s_q[kk * 4]);
  const int lane = tid & 63, wid = tid >> 6;
  float mx = acc;
  for (int off = 32; off; off >>= 1) mx = fmaxf(mx, __shfl_xor(mx, off, 64));
  if (lane == 0) s_red[wid] = mx;
  __syncthreads();
  float gmx = s_red[0];
#pragma unroll
  for (int i = 1; i < 8; ++i) gmx = fmaxf(gmx, s_red[i]);
  const float e = expf(acc - gmx);
  float sum = e;
  for (int off = 32; off; off >>= 1) sum += __shfl_xor(sum, off, 64);
  if (lane == 0) s_red[8 + wid] = sum;
  __syncthreads();
  float gs = 0.f;
#pragma unroll
  for (int i = 0; i < 8; ++i) gs += s_red[8 + i];
  wtab[c * N_ + n] = e / gs;
}

// ============ kG: etab/atab[id][d], 129 blocks x 8 ids =====================
__global__ __launch_bounds__(512) void kG(const float* __restrict__ iemb,
                                          const float* __restrict__ We,
                                          const float* __restrict__ be,
                                          const float* __restrict__ Wa,
                                          const float* __restrict__ ba,
                                          float* __restrict__ etab,
                                          float* __restrict__ atab) {
  __shared__ float s_v[8 * DV_];
  const int tid = threadIdx.x, bi = blockIdx.x;
  {
    const int j = tid >> 6, c4 = tid & 63;
    const int id = bi * 8 + j;
    float4 v = make_float4(0.f, 0.f, 0.f, 0.f);
    if (id >= 1 && id < NIID) v = ((const float4*)iemb)[(size_t)id * 64 + c4];
    *(float4*)&s_v[j * DV_ + c4 * 4] = v;
  }
  __syncthreads();
  const int gate = tid >> 8, d = tid & 255;
  const float4* wr = (const float4*)((gate ? Wa : We) + d * DV_);
  float acc[8];
#pragma unroll
  for (int j = 0; j < 8; ++j) acc[j] = 0.f;
  for (int kk = 0; kk < DV_ / 4; ++kk) {
    const float4 w4 = wr[kk];
#pragma unroll
    for (int j = 0; j < 8; ++j) acc[j] += dot4(w4, *(const float4*)&s_v[j * DV_ + kk * 4]);
  }
  const float bias = gate ? ba[d] : be[d];
#pragma unroll
  for (int j = 0; j < 8; ++j) {
    const int id = bi * 8 + j;
    if (id < NIID) {
      if (gate) atab[(size_t)id * DV_ + d] = tanhf(acc[j] + bias);
      else      etab[(size_t)id * DV_ + d] = 1.f / (1.f + expf(-(acc[j] + bias)));
    }
  }
}

// ============ kS: sparse DS+VALU recurrence, 512 blocks x 1024 thr =========
// R24-exact. block = (b, ch); wave owns 16 rows as NAMED float4 registers;
// anti-spill invariants: unroll-1 j-loop, tid<256 float4 unroll-4 drain.
#define ROWOP(mr, wsel)                                   \
  do {                                                    \
    const float w_ = (wsel);                              \
    racc.x = fmaf(w_, mr.x, racc.x);                      \
    racc.y = fmaf(w_, mr.y, racc.y);                      \
    racc.z = fmaf(w_, mr.z, racc.z);                      \
    racc.w = fmaf(w_, mr.w, racc.w);                      \
    mr.x = fmaf(-w_, fmaf(e4.x, mr.x, -a4.x), mr.x);      \
    mr.y = fmaf(-w_, fmaf(e4.y, mr.y, -a4.y), mr.y);      \
    mr.z = fmaf(-w_, fmaf(e4.z, mr.z, -a4.z), mr.z);      \
    mr.w = fmaf(-w_, fmaf(e4.w, mr.w, -a4.w), mr.w);      \
  } while (0)

#define GRP4(wq, A, B, C, D)                                              \
  do {                                                                    \
    const float gmx_ = fmaxf(fmaxf(wq.x, wq.y), fmaxf(wq.z, wq.w));       \
    if (__int_as_float(__builtin_amdgcn_readfirstlane(                    \
            __float_as_int(gmx_))) > EPSW) {                              \
      ROWOP(A, wq.x); ROWOP(B, wq.y); ROWOP(C, wq.z); ROWOP(D, wq.w);     \
    }                                                                     \
  } while (0)

__global__ __launch_bounds__(1024)
__attribute__((amdgpu_waves_per_eu(4, 4))) void kS(
    const int* __restrict__ concepts, const int* __restrict__ inter,
    const float* __restrict__ Vmem, const float* __restrict__ wtab,
    const float* __restrict__ etab, const float* __restrict__ atab,
    h16* __restrict__ rpart) {
  __shared__ float s_w[TB_][DV_];        // 16 KB: w[t][block's 256-row chunk]
  __shared__ float s_e[TB_][DV_];        // 16 KB
  __shared__ float s_a[TB_][DV_];        // 16 KB
  __shared__ float s_racc[4][16][DV_];   // 64 KB: 4 steps x 16 wave-partials
  const int tid = threadIdx.x, bx = blockIdx.x;
  const int b = bx >> 1, ch = bx & 1;
  const int lane = tid & 63, wv = tid >> 6;  // 16 waves
  const int row0 = ch * 256 + __builtin_amdgcn_readfirstlane(wv * 16);
  float4 m0, m1, m2, m3, m4, m5, m6, m7, m8, m9, m10, m11, m12, m13, m14, m15;
  {
    const float4* vm4 = (const float4*)Vmem + (size_t)row0 * 64 + lane;
    m0 = vm4[0 * 64];   m1 = vm4[1 * 64];   m2 = vm4[2 * 64];   m3 = vm4[3 * 64];
    m4 = vm4[4 * 64];   m5 = vm4[5 * 64];   m6 = vm4[6 * 64];   m7 = vm4[7 * 64];
    m8 = vm4[8 * 64];   m9 = vm4[9 * 64];   m10 = vm4[10 * 64]; m11 = vm4[11 * 64];
    m12 = vm4[12 * 64]; m13 = vm4[13 * 64]; m14 = vm4[14 * 64]; m15 = vm4[15 * 64];
  }
  const int* cb = concepts + b * T_;
  const int* ib = inter + b * T_;
  const float4* wtab4 = (const float4*)wtab;
  const float4* etab4 = (const float4*)etab;
  const float4* atab4 = (const float4*)atab;
  h16* rp = rpart + (size_t)ch * NP_ * DV_ + (size_t)b * T_ * DV_;

  // cooperative tile staging: w/e/a rows for 16 steps (3 float4 loads/thread,
  // tables are L2-resident).
  auto stage = [&](int t0) {
    const int tl = tid >> 6, c4 = tid & 63;
    const int cv = cb[t0 + tl];
    const int iv = ib[t0 + tl];
    *(float4*)&s_w[tl][c4 * 4] = wtab4[(size_t)cv * 128 + ch * 64 + c4];
    *(float4*)&s_e[tl][c4 * 4] = etab4[(size_t)iv * 64 + c4];
    *(float4*)&s_a[tl][c4 * 4] = atab4[(size_t)iv * 64 + c4];
  };

  stage(0);
  __syncthreads();

  for (int t0 = 0; t0 < T_; t0 += TB_) {
    for (int s = 0; s < 4; ++s) {  // 4 sub-tiles of 4 steps
#pragma unroll 1                   // CAP PRESSURE: one step's LDS reads live
      for (int j = 0; j < 4; ++j) {
        const int tl = s * 4 + j;
        // wave-uniform broadcast reads: this wave's 16 w values
        const float* wrow = &s_w[tl][wv * 16];
        const float4 wq0 = *(const float4*)(wrow + 0);
        const float4 wq1 = *(const float4*)(wrow + 4);
        const float4 wq2 = *(const float4*)(wrow + 8);
        const float4 wq3 = *(const float4*)(wrow + 12);
        const float4 e4 = *(const float4*)&s_e[tl][lane * 4];
        const float4 a4 = *(const float4*)&s_a[tl][lane * 4];
        float4 racc = make_float4(0.f, 0.f, 0.f, 0.f);
        GRP4(wq0, m0, m1, m2, m3);
        GRP4(wq1, m4, m5, m6, m7);
        GRP4(wq2, m8, m9, m10, m11);
        GRP4(wq3, m12, m13, m14, m15);
        // plain per-wave partial write — no atomics
        *(float4*)&s_racc[j][wv][lane * 4] = racc;
      }
      __syncthreads();
      // overlap next-tile staging with the drain (independent LDS regions)
      if (s == 3 && t0 + TB_ < T_) stage(t0 + TB_);
      if (tid < 256) {
        // drain: 4 waves reduce 16 wave-partials; unroll 4 bounds live temps.
        const int j = tid >> 6, l = tid & 63;
        float4 acc = make_float4(0.f, 0.f, 0.f, 0.f);
#pragma unroll 4
        for (int w2 = 0; w2 < 16; ++w2) {
          const float4 v = *(const float4*)&s_racc[j][w2][l * 4];
          acc.x += v.x; acc.y += v.y; acc.z += v.z; acc.w += v.w;
        }
        *(half4*)(rp + (size_t)(t0 + s * 4 + j) * DV_ + l * 4) = f2h(acc);
      }
      __syncthreads();
    }
  }
}

// ============ kM: MLP head, 2048 blocks x 1024 thr =========================
// 16 waves x 4 p-rows (was 8 x 8): same LDS (137 KB), 4 waves/SIMD instead
// of 2. Arithmetic order per (p, j) unchanged -> bit-identical output.
#define MP_ 64
__global__ __launch_bounds__(1024) void kM(const int* __restrict__ concepts,
                                           const float* __restrict__ cemb,
                                           const h16* __restrict__ rpart,
                                           const float* __restrict__ W1,
                                           const float* __restrict__ b1,
                                           const float* __restrict__ W2,
                                           const float* __restrict__ b2,
                                           const float* __restrict__ W3,
                                           const float* __restrict__ b3,
                                           float* __restrict__ out) {
  __shared__ float s_f[MP_][DV_ + DK_];  // 80 KB
  __shared__ h16 s_W1[S_][324];          // 40.5 KB (padded)
  __shared__ float s_h1[16][4][S_];      // 16 KB
  __shared__ int s_c[MP_];
  const int tid = threadIdx.x, g = blockIdx.x;
  const int lane = tid & 63, wv = tid >> 6;  // 16 waves
  if (tid < MP_) s_c[tid] = concepts[g * MP_ + tid];
  {
    // W1 staging: 64 rows (j = tid>>4), 16 threads/row, 5 float4 each
    const int j = tid >> 4, f0 = tid & 15;
    const float4* w1r = (const float4*)(W1 + j * 320);
#pragma unroll
    for (int i = 0; i < 5; ++i) {
      const int k4 = f0 + i * 16;
      *(half4*)&s_W1[j][k4 * 4] = f2h(w1r[k4]);
    }
  }
  __syncthreads();
  {
    const half4* p0 = (const half4*)rpart;
    const half4* p1 = p0 + (size_t)NP_ * 64;
#pragma unroll
    for (int i = 0; i < 4; ++i) {
      const int idx = tid + i * 1024, p = idx >> 6, c4 = idx & 63;
      const size_t off = (size_t)(g * MP_ + p) * 64 + c4;
      const float4 v0 = h2f(p0[off]);
      const float4 v1 = h2f(p1[off]);
      *(float4*)&s_f[p][c4 * 4] =
          make_float4(v0.x + v1.x, v0.y + v1.y, v0.z + v1.z, v0.w + v1.w);
    }
    // cemb tail: 64 p-rows x 16 float4 = 1024 -> one load per thread
    const float4* ce4 = (const float4*)cemb;
    const float4 z = make_float4(0.f, 0.f, 0.f, 0.f);
    const int p = tid >> 4, k4 = tid & 15;
    const int c = s_c[p];
    *(float4*)&s_f[p][DV_ + k4 * 4] = c ? ce4[c * 16 + k4] : z;
  }
  __syncthreads();
  const int j = lane;
  float acc[4];
  {
    const float b1j = b1[j];
#pragma unroll
    for (int p = 0; p < 4; ++p) acc[p] = b1j;
  }
  for (int k4 = 0; k4 < 80; ++k4) {
    const float4 w4 = h2f(*(const half4*)&s_W1[j][k4 * 4]);
#pragma unroll
    for (int p = 0; p < 4; ++p)
      acc[p] += dot4(w4, *(const float4*)&s_f[wv * 4 + p][k4 * 4]);
  }
#pragma unroll
  for (int p = 0; p < 4; ++p) s_h1[wv][p][j] = fmaxf(acc[p], 0.f);
  __syncthreads();
  {
    const float b2j = b2[j];
#pragma unroll
    for (int p = 0; p < 4; ++p) acc[p] = b2j;
  }
  const float4* w2r = (const float4*)(W2 + j * S_);
#pragma unroll
  for (int k4 = 0; k4 < S_ / 4; ++k4) {
    const float4 w4 = w2r[k4];
#pragma unroll
    for (int p = 0; p < 4; ++p)
      acc[p] += dot4(w4, *(const float4*)&s_h1[wv][p][k4 * 4]);
  }
  const float w3j = W3[j], b3v = b3[0];
#pragma unroll
  for (int p = 0; p < 4; ++p) {
    float pp = fmaxf(acc[p], 0.f) * w3j;
    for (int off = 32; off; off >>= 1) pp += __shfl_xor(pp, off, 64);
    if (lane == 0)
      out[g * MP_ + wv * 4 + p] = 1.f / (1.f + expf(-(pp + b3v)));
  }
}

extern "C" void kernel_launch(void* const* d_in, const int* in_sizes, int n_in,
                              void* d_out, int out_size, void* d_ws, size_t ws_size,
                              hipStream_t stream) {
  const int* concepts = (const int*)d_in[0];
  const int* interactions = (const int*)d_in[1];
  const float* Kmem = (const float*)d_in[2];
  const float* Vmem = (const float*)d_in[3];
  const float* cemb = (const float*)d_in[4];
  const float* iemb = (const float*)d_in[5];
  const float* We = (const float*)d_in[6];
  const float* be = (const float*)d_in[7];
  const float* Wa = (const float*)d_in[8];
  const float* ba = (const float*)d_in[9];
  const float* W1 = (const float*)d_in[10];
  const float* b1 = (const float*)d_in[11];
  const float* W2 = (const float*)d_in[12];
  const float* b2 = (const float*)d_in[13];
  const float* W3 = (const float*)d_in[14];
  const float* b3 = (const float*)d_in[15];
  float* out = (float*)d_out;

  const size_t sz_w = (size_t)NCID * N_ * 4;
  const size_t sz_e = (size_t)NIID * DV_ * 4;
  float* wtab = (float*)d_ws;
  float* etab = (float*)((char*)d_ws + sz_w);
  float* atab = (float*)((char*)d_ws + sz_w + sz_e);
  h16* rpart = (h16*)((char*)d_ws + sz_w + 2 * sz_e);  // 2 x 64 MiB

  kW<<<dim3(NCID), dim3(512), 0, stream>>>(Kmem, cemb, wtab);
  kG<<<dim3((NIID + 7) / 8), dim3(512), 0, stream>>>(iemb, We, be, Wa, ba, etab, atab);
  kS<<<dim3(B_ * 2), dim3(1024), 0, stream>>>(concepts, interactions, Vmem,
                                              wtab, etab, atab, rpart);
  kM<<<dim3(NP_ / MP_), dim3(1024), 0, stream>>>(concepts, cemb, rpart,
                                                 W1, b1, W2, b2, W3, b3, out);
}

// Round 12
// 1276.800 us; speedup vs baseline: 1.1430x; 1.1430x over previous
//
#include <hip/hip_runtime.h>

// DKVMN forward, round 26 — kM re-orientation: lane=p, SGPR-W1, b32 LDS.
// R25 post-mortem: doubling kM's waves/SIMD was NEUTRAL -> not latency-bound.
// Real structure: layer-1 issued ~1280 4-way-conflicted b128 (W1, lane-stride
// 648B) + ~5120 broadcast b128 (f) per block; LDS pipe is per-CU so extra
// waves add nothing. R26 removes kM from the LDS pipe: lane = sample p, wave
// owns 4 output cols j -> W1[j][k] is wave-uniform = scalar s_load from
// GLOBAL (proven kS-wtab pattern, zero LDS); f read per-lane ds_read_b32 at
// odd dword stride 321 -> conflict-free. s_h1 (65) / s_red (17) odd strides
// too. All fp32; fdot2/bit_cast stays banned (R21/22 deterministic fail).
// kS/kW/kG byte-identical to R24/R25 green.
//   kW: wtab[513][512] fp32   kG: etab/atab[1025][256] fp32   (3.2 MB, hot)
//   kS: 512 blocks x 1024 thr; named m0..m15; unroll-1 j-loop; tid<256
//       float4 unroll-4 drain; GRP4 skip EPSW=1e-6.  (920 us green)
//   kM: 2048 blocks x 1024 thr; LDS 103 KB (s_f[64][321] fp32 + s_h1 + s_red).
// ws = 3.2 MB + 128 MiB.

#define B_ 256
#define T_ 512
#define N_ 512
#define DK_ 64
#define DV_ 256
#define S_ 64
#define NP_ (B_ * T_)
#define NCID 513
#define NIID 1025
#define TB_ 16
#define EPSW 1e-6f

typedef _Float16 h16;
typedef __attribute__((ext_vector_type(4))) _Float16 half4;

__device__ __forceinline__ float dot4(float4 a, float4 b) {
  return a.x * b.x + a.y * b.y + a.z * b.z + a.w * b.w;
}
__device__ __forceinline__ float4 h2f(half4 h) {
  return make_float4((float)h.x, (float)h.y, (float)h.z, (float)h.w);
}
__device__ __forceinline__ half4 f2h(float4 f) {
  half4 h;
  h.x = (h16)f.x; h.y = (h16)f.y; h.z = (h16)f.z; h.w = (h16)f.w;
  return h;
}

// ============ kW: wtab[c][n] = softmax_n(q_c . K_n), 513 blocks ============
__global__ __launch_bounds__(512) void kW(const float* __restrict__ Kmem,
                                          const float* __restrict__ cemb,
                                          float* __restrict__ wtab) {
  __shared__ float s_q[DK_];
  __shared__ float s_red[16];
  const int tid = threadIdx.x, c = blockIdx.x;
  if (tid < DK_) s_q[tid] = c ? cemb[c * DK_ + tid] : 0.f;
  __syncthreads();
  const int n = tid;
  const float4* kr = (const float4*)(Kmem + n * DK_);
  float acc = 0.f;
#pragma unroll
  for (int kk = 0; kk < DK_ / 4; ++kk) acc += dot4(kr[kk], *(const float4*)&s_q[kk * 4]);
  const int lane = tid & 63, wid = tid >> 6;
  float mx = acc;
  for (int off = 32; off; off >>= 1) mx = fmaxf(mx, __shfl_xor(mx, off, 64));
  if (lane == 0) s_red[wid] = mx;
  __syncthreads();
  float gmx = s_red[0];
#pragma unroll
  for (int i = 1; i < 8; ++i) gmx = fmaxf(gmx, s_red[i]);
  const float e = expf(acc - gmx);
  float sum = e;
  for (int off = 32; off; off >>= 1) sum += __shfl_xor(sum, off, 64);
  if (lane == 0) s_red[8 + wid] = sum;
  __syncthreads();
  float gs = 0.f;
#pragma unroll
  for (int i = 0; i < 8; ++i) gs += s_red[8 + i];
  wtab[c * N_ + n] = e / gs;
}

// ============ kG: etab/atab[id][d], 129 blocks x 8 ids =====================
__global__ __launch_bounds__(512) void kG(const float* __restrict__ iemb,
                                          const float* __restrict__ We,
                                          const float* __restrict__ be,
                                          const float* __restrict__ Wa,
                                          const float* __restrict__ ba,
                                          float* __restrict__ etab,
                                          float* __restrict__ atab) {
  __shared__ float s_v[8 * DV_];
  const int tid = threadIdx.x, bi = blockIdx.x;
  {
    const int j = tid >> 6, c4 = tid & 63;
    const int id = bi * 8 + j;
    float4 v = make_float4(0.f, 0.f, 0.f, 0.f);
    if (id >= 1 && id < NIID) v = ((const float4*)iemb)[(size_t)id * 64 + c4];
    *(float4*)&s_v[j * DV_ + c4 * 4] = v;
  }
  __syncthreads();
  const int gate = tid >> 8, d = tid & 255;
  const float4* wr = (const float4*)((gate ? Wa : We) + d * DV_);
  float acc[8];
#pragma unroll
  for (int j = 0; j < 8; ++j) acc[j] = 0.f;
  for (int kk = 0; kk < DV_ / 4; ++kk) {
    const float4 w4 = wr[kk];
#pragma unroll
    for (int j = 0; j < 8; ++j) acc[j] += dot4(w4, *(const float4*)&s_v[j * DV_ + kk * 4]);
  }
  const float bias = gate ? ba[d] : be[d];
#pragma unroll
  for (int j = 0; j < 8; ++j) {
    const int id = bi * 8 + j;
    if (id < NIID) {
      if (gate) atab[(size_t)id * DV_ + d] = tanhf(acc[j] + bias);
      else      etab[(size_t)id * DV_ + d] = 1.f / (1.f + expf(-(acc[j] + bias)));
    }
  }
}

// ============ kS: sparse DS+VALU recurrence, 512 blocks x 1024 thr =========
// R24-exact. block = (b, ch); wave owns 16 rows as NAMED float4 registers;
// anti-spill invariants: unroll-1 j-loop, tid<256 float4 unroll-4 drain.
#define ROWOP(mr, wsel)                                   \
  do {                                                    \
    const float w_ = (wsel);                              \
    racc.x = fmaf(w_, mr.x, racc.x);                      \
    racc.y = fmaf(w_, mr.y, racc.y);                      \
    racc.z = fmaf(w_, mr.z, racc.z);                      \
    racc.w = fmaf(w_, mr.w, racc.w);                      \
    mr.x = fmaf(-w_, fmaf(e4.x, mr.x, -a4.x), mr.x);      \
    mr.y = fmaf(-w_, fmaf(e4.y, mr.y, -a4.y), mr.y);      \
    mr.z = fmaf(-w_, fmaf(e4.z, mr.z, -a4.z), mr.z);      \
    mr.w = fmaf(-w_, fmaf(e4.w, mr.w, -a4.w), mr.w);      \
  } while (0)

#define GRP4(wq, A, B, C, D)                                              \
  do {                                                                    \
    const float gmx_ = fmaxf(fmaxf(wq.x, wq.y), fmaxf(wq.z, wq.w));       \
    if (__int_as_float(__builtin_amdgcn_readfirstlane(                    \
            __float_as_int(gmx_))) > EPSW) {                              \
      ROWOP(A, wq.x); ROWOP(B, wq.y); ROWOP(C, wq.z); ROWOP(D, wq.w);     \
    }                                                                     \
  } while (0)

__global__ __launch_bounds__(1024)
__attribute__((amdgpu_waves_per_eu(4, 4))) void kS(
    const int* __restrict__ concepts, const int* __restrict__ inter,
    const float* __restrict__ Vmem, const float* __restrict__ wtab,
    const float* __restrict__ etab, const float* __restrict__ atab,
    h16* __restrict__ rpart) {
  __shared__ float s_w[TB_][DV_];        // 16 KB: w[t][block's 256-row chunk]
  __shared__ float s_e[TB_][DV_];        // 16 KB
  __shared__ float s_a[TB_][DV_];        // 16 KB
  __shared__ float s_racc[4][16][DV_];   // 64 KB: 4 steps x 16 wave-partials
  const int tid = threadIdx.x, bx = blockIdx.x;
  const int b = bx >> 1, ch = bx & 1;
  const int lane = tid & 63, wv = tid >> 6;  // 16 waves
  const int row0 = ch * 256 + __builtin_amdgcn_readfirstlane(wv * 16);
  float4 m0, m1, m2, m3, m4, m5, m6, m7, m8, m9, m10, m11, m12, m13, m14, m15;
  {
    const float4* vm4 = (const float4*)Vmem + (size_t)row0 * 64 + lane;
    m0 = vm4[0 * 64];   m1 = vm4[1 * 64];   m2 = vm4[2 * 64];   m3 = vm4[3 * 64];
    m4 = vm4[4 * 64];   m5 = vm4[5 * 64];   m6 = vm4[6 * 64];   m7 = vm4[7 * 64];
    m8 = vm4[8 * 64];   m9 = vm4[9 * 64];   m10 = vm4[10 * 64]; m11 = vm4[11 * 64];
    m12 = vm4[12 * 64]; m13 = vm4[13 * 64]; m14 = vm4[14 * 64]; m15 = vm4[15 * 64];
  }
  const int* cb = concepts + b * T_;
  const int* ib = inter + b * T_;
  const float4* wtab4 = (const float4*)wtab;
  const float4* etab4 = (const float4*)etab;
  const float4* atab4 = (const float4*)atab;
  h16* rp = rpart + (size_t)ch * NP_ * DV_ + (size_t)b * T_ * DV_;

  // cooperative tile staging: w/e/a rows for 16 steps (3 float4 loads/thread,
  // tables are L2-resident).
  auto stage = [&](int t0) {
    const int tl = tid >> 6, c4 = tid & 63;
    const int cv = cb[t0 + tl];
    const int iv = ib[t0 + tl];
    *(float4*)&s_w[tl][c4 * 4] = wtab4[(size_t)cv * 128 + ch * 64 + c4];
    *(float4*)&s_e[tl][c4 * 4] = etab4[(size_t)iv * 64 + c4];
    *(float4*)&s_a[tl][c4 * 4] = atab4[(size_t)iv * 64 + c4];
  };

  stage(0);
  __syncthreads();

  for (int t0 = 0; t0 < T_; t0 += TB_) {
    for (int s = 0; s < 4; ++s) {  // 4 sub-tiles of 4 steps
#pragma unroll 1                   // CAP PRESSURE: one step's LDS reads live
      for (int j = 0; j < 4; ++j) {
        const int tl = s * 4 + j;
        // wave-uniform broadcast reads: this wave's 16 w values
        const float* wrow = &s_w[tl][wv * 16];
        const float4 wq0 = *(const float4*)(wrow + 0);
        const float4 wq1 = *(const float4*)(wrow + 4);
        const float4 wq2 = *(const float4*)(wrow + 8);
        const float4 wq3 = *(const float4*)(wrow + 12);
        const float4 e4 = *(const float4*)&s_e[tl][lane * 4];
        const float4 a4 = *(const float4*)&s_a[tl][lane * 4];
        float4 racc = make_float4(0.f, 0.f, 0.f, 0.f);
        GRP4(wq0, m0, m1, m2, m3);
        GRP4(wq1, m4, m5, m6, m7);
        GRP4(wq2, m8, m9, m10, m11);
        GRP4(wq3, m12, m13, m14, m15);
        // plain per-wave partial write — no atomics
        *(float4*)&s_racc[j][wv][lane * 4] = racc;
      }
      __syncthreads();
      // overlap next-tile staging with the drain (independent LDS regions)
      if (s == 3 && t0 + TB_ < T_) stage(t0 + TB_);
      if (tid < 256) {
        // drain: 4 waves reduce 16 wave-partials; unroll 4 bounds live temps.
        const int j = tid >> 6, l = tid & 63;
        float4 acc = make_float4(0.f, 0.f, 0.f, 0.f);
#pragma unroll 4
        for (int w2 = 0; w2 < 16; ++w2) {
          const float4 v = *(const float4*)&s_racc[j][w2][l * 4];
          acc.x += v.x; acc.y += v.y; acc.z += v.z; acc.w += v.w;
        }
        *(half4*)(rp + (size_t)(t0 + s * 4 + j) * DV_ + l * 4) = f2h(acc);
      }
      __syncthreads();
    }
  }
}

// ============ kM: MLP head, 2048 blocks x 1024 thr, lane=p orientation =====
// Wave w owns output cols j = 4w..4w+3 for ALL 64 samples; lane = sample p.
// W1/W2/W3/b* are wave-uniform -> scalar loads from global (SMEM pipe).
// f reads: per-lane ds_read_b32, odd stride 321 -> conflict-free.
#define MP_ 64
#define SF_ 321  // s_f dword stride (odd -> bank-conflict-free b32)
#define SH_ 65   // s_h1 dword stride (odd)
#define SR_ 17   // s_red dword stride (odd)
__global__ __launch_bounds__(1024) void kM(const int* __restrict__ concepts,
                                           const float* __restrict__ cemb,
                                           const h16* __restrict__ rpart,
                                           const float* __restrict__ W1,
                                           const float* __restrict__ b1,
                                           const float* __restrict__ W2,
                                           const float* __restrict__ b2,
                                           const float* __restrict__ W3,
                                           const float* __restrict__ b3,
                                           float* __restrict__ out) {
  __shared__ float s_f[MP_][SF_];   // 82.2 KB: f = [r(256) | q(64)] fp32
  __shared__ float s_h1[MP_][SH_];  // 16.6 KB
  __shared__ float s_red[MP_][SR_]; // 4.4 KB
  __shared__ int s_c[MP_];
  const int tid = threadIdx.x, g = blockIdx.x;
  const int lane = tid & 63, wv = tid >> 6;  // 16 waves; lane = sample p
  if (tid < MP_) s_c[tid] = concepts[g * MP_ + tid];
  __syncthreads();
  {
    // stage f rows: r = p0 + p1 (fp16 partial sums), then q = cemb[c].
    const half4* p0 = (const half4*)rpart;
    const half4* p1 = p0 + (size_t)NP_ * 64;
#pragma unroll
    for (int i = 0; i < 4; ++i) {
      const int idx = tid + i * 1024, p = idx >> 6, c4 = idx & 63;
      const size_t off = (size_t)(g * MP_ + p) * 64 + c4;
      const float4 v0 = h2f(p0[off]);
      const float4 v1 = h2f(p1[off]);
      s_f[p][c4 * 4 + 0] = v0.x + v1.x;
      s_f[p][c4 * 4 + 1] = v0.y + v1.y;
      s_f[p][c4 * 4 + 2] = v0.z + v1.z;
      s_f[p][c4 * 4 + 3] = v0.w + v1.w;
    }
    const float4* ce4 = (const float4*)cemb;
    const float4 z = make_float4(0.f, 0.f, 0.f, 0.f);
    const int p = tid >> 4, k4 = tid & 15;
    const int c = s_c[p];
    const float4 q = c ? ce4[c * 16 + k4] : z;
    s_f[p][DV_ + k4 * 4 + 0] = q.x;
    s_f[p][DV_ + k4 * 4 + 1] = q.y;
    s_f[p][DV_ + k4 * 4 + 2] = q.z;
    s_f[p][DV_ + k4 * 4 + 3] = q.w;
  }
  __syncthreads();
  // ---- layer 1: h1[p][j] = relu(b1[j] + sum_k W1[j][k] f[p][k]) ----
  {
    const int j0 = wv * 4;  // wave-uniform
    const float* W1r0 = W1 + (size_t)(j0 + 0) * 320;
    const float* W1r1 = W1 + (size_t)(j0 + 1) * 320;
    const float* W1r2 = W1 + (size_t)(j0 + 2) * 320;
    const float* W1r3 = W1 + (size_t)(j0 + 3) * 320;
    float a0 = b1[j0 + 0], a1 = b1[j0 + 1], a2 = b1[j0 + 2], a3 = b1[j0 + 3];
#pragma unroll 1
    for (int k4 = 0; k4 < 80; ++k4) {
      const float4 w0 = *(const float4*)(W1r0 + k4 * 4);  // s_load (uniform)
      const float4 w1 = *(const float4*)(W1r1 + k4 * 4);
      const float4 w2 = *(const float4*)(W1r2 + k4 * 4);
      const float4 w3 = *(const float4*)(W1r3 + k4 * 4);
      const float f0 = s_f[lane][k4 * 4 + 0];  // conflict-free b32
      const float f1 = s_f[lane][k4 * 4 + 1];
      const float f2 = s_f[lane][k4 * 4 + 2];
      const float f3 = s_f[lane][k4 * 4 + 3];
      a0 = fmaf(w0.x, f0, fmaf(w0.y, f1, fmaf(w0.z, f2, fmaf(w0.w, f3, a0))));
      a1 = fmaf(w1.x, f0, fmaf(w1.y, f1, fmaf(w1.z, f2, fmaf(w1.w, f3, a1))));
      a2 = fmaf(w2.x, f0, fmaf(w2.y, f1, fmaf(w2.z, f2, fmaf(w2.w, f3, a2))));
      a3 = fmaf(w3.x, f0, fmaf(w3.y, f1, fmaf(w3.z, f2, fmaf(w3.w, f3, a3))));
    }
    s_h1[lane][j0 + 0] = fmaxf(a0, 0.f);
    s_h1[lane][j0 + 1] = fmaxf(a1, 0.f);
    s_h1[lane][j0 + 2] = fmaxf(a2, 0.f);
    s_h1[lane][j0 + 3] = fmaxf(a3, 0.f);
  }
  __syncthreads();
  // ---- layer 2 + W3 partial: wave handles j2 = 4wv..4wv+3 ----
  {
    const int j0 = wv * 4;
    const float* W2r0 = W2 + (size_t)(j0 + 0) * 64;
    const float* W2r1 = W2 + (size_t)(j0 + 1) * 64;
    const float* W2r2 = W2 + (size_t)(j0 + 2) * 64;
    const float* W2r3 = W2 + (size_t)(j0 + 3) * 64;
    float a0 = b2[j0 + 0], a1 = b2[j0 + 1], a2 = b2[j0 + 2], a3 = b2[j0 + 3];
#pragma unroll 1
    for (int k4 = 0; k4 < 16; ++k4) {
      const float4 w0 = *(const float4*)(W2r0 + k4 * 4);
      const float4 w1 = *(const float4*)(W2r1 + k4 * 4);
      const float4 w2 = *(const float4*)(W2r2 + k4 * 4);
      const float4 w3 = *(const float4*)(W2r3 + k4 * 4);
      const float h0 = s_h1[lane][k4 * 4 + 0];
      const float h1v = s_h1[lane][k4 * 4 + 1];
      const float h2v = s_h1[lane][k4 * 4 + 2];
      const float h3 = s_h1[lane][k4 * 4 + 3];
      a0 = fmaf(w0.x, h0, fmaf(w0.y, h1v, fmaf(w0.z, h2v, fmaf(w0.w, h3, a0))));
      a1 = fmaf(w1.x, h0, fmaf(w1.y, h1v, fmaf(w1.z, h2v, fmaf(w1.w, h3, a1))));
      a2 = fmaf(w2.x, h0, fmaf(w2.y, h1v, fmaf(w2.z, h2v, fmaf(w2.w, h3, a2))));
      a3 = fmaf(w3.x, h0, fmaf(w3.y, h1v, fmaf(w3.z, h2v, fmaf(w3.w, h3, a3))));
    }
    const float p3 = fmaxf(a0, 0.f) * W3[j0 + 0] + fmaxf(a1, 0.f) * W3[j0 + 1] +
                     fmaxf(a2, 0.f) * W3[j0 + 2] + fmaxf(a3, 0.f) * W3[j0 + 3];
    s_red[lane][wv] = p3;
  }
  __syncthreads();
  // ---- final reduce over 16 waves + sigmoid, wave 0 only ----
  if (wv == 0) {
    float s = b3[0];
#pragma unroll
    for (int w = 0; w < 16; ++w) s += s_red[lane][w];
    out[g * MP_ + lane] = 1.f / (1.f + expf(-s));
  }
}

extern "C" void kernel_launch(void* const* d_in, const int* in_sizes, int n_in,
                              void* d_out, int out_size, void* d_ws, size_t ws_size,
                              hipStream_t stream) {
  const int* concepts = (const int*)d_in[0];
  const int* interactions = (const int*)d_in[1];
  const float* Kmem = (const float*)d_in[2];
  const float* Vmem = (const float*)d_in[3];
  const float* cemb = (const float*)d_in[4];
  const float* iemb = (const float*)d_in[5];
  const float* We = (const float*)d_in[6];
  const float* be = (const float*)d_in[7];
  const float* Wa = (const float*)d_in[8];
  const float* ba = (const float*)d_in[9];
  const float* W1 = (const float*)d_in[10];
  const float* b1 = (const float*)d_in[11];
  const float* W2 = (const float*)d_in[12];
  const float* b2 = (const float*)d_in[13];
  const float* W3 = (const float*)d_in[14];
  const float* b3 = (const float*)d_in[15];
  float* out = (float*)d_out;

  const size_t sz_w = (size_t)NCID * N_ * 4;
  const size_t sz_e = (size_t)NIID * DV_ * 4;
  float* wtab = (float*)d_ws;
  float* etab = (float*)((char*)d_ws + sz_w);
  float* atab = (float*)((char*)d_ws + sz_w + sz_e);
  h16* rpart = (h16*)((char*)d_ws + sz_w + 2 * sz_e);  // 2 x 64 MiB

  kW<<<dim3(NCID), dim3(512), 0, stream>>>(Kmem, cemb, wtab);
  kG<<<dim3((NIID + 7) / 8), dim3(512), 0, stream>>>(iemb, We, be, Wa, ba, etab, atab);
  kS<<<dim3(B_ * 2), dim3(1024), 0, stream>>>(concepts, interactions, Vmem,
                                              wtab, etab, atab, rpart);
  kM<<<dim3(NP_ / MP_), dim3(1024), 0, stream>>>(concepts, cemb, rpart,
                                                 W1, b1, W2, b2, W3, b3, out);
}

// Round 13
// 1257.879 us; speedup vs baseline: 1.1602x; 1.0150x over previous
//
#include <hip/hip_runtime.h>

// DKVMN forward, round 27 — resurrect the kS ring (single barrier / 4 steps).
// R26 green: total 1277, kS 897 (VALUBusy 64% -> ~320 us stall in 2-barrier
// cadence: 256 syncs/gen + drain by 4 waves while 12 idle). R22's bit-identical
// absmax across DIFFERENT kS kernels exonerated R21's ring — the fail was kM's
// fdot2 (banned, replaced in R26). Re-audit of the ring finds no race:
// compute reads slots {t0..t0+3}&7 vs stage writes {t0+4..t0+7}&7 (disjoint);
// drain reads s_racc[win^1] vs compute writes s_racc[win] (disjoint); one
// barrier per iteration orders cross-iteration hazards; stage4's arr/r are
// wave-uniform. R27 = R26 with ONLY kS restructured: 8-slot w/e/a rings
// (24 KB) + s_racc[2] dbuf (128 KB, 152 KB total), 1 barrier per 4 steps,
// drain (waves 0-3) overlapped with staging (waves 4-15). Anti-spill
// invariants kept: named m0..m15, unroll-1 j-loop, tid<256 f4 unroll-4 drain.
// WRITE_SIZE is the spill tripwire (must stay 131072 KB).
//   kW: wtab[513][512] fp32   kG: etab/atab[1025][256] fp32   (3.2 MB, hot)
//   kM: R26-exact lane=p orientation (SGPR weights, odd-stride b32 LDS).
// ws = 3.2 MB + 128 MiB.

#define B_ 256
#define T_ 512
#define N_ 512
#define DK_ 64
#define DV_ 256
#define S_ 64
#define NP_ (B_ * T_)
#define NCID 513
#define NIID 1025
#define EPSW 1e-6f

typedef _Float16 h16;
typedef __attribute__((ext_vector_type(4))) _Float16 half4;

__device__ __forceinline__ float dot4(float4 a, float4 b) {
  return a.x * b.x + a.y * b.y + a.z * b.z + a.w * b.w;
}
__device__ __forceinline__ float4 h2f(half4 h) {
  return make_float4((float)h.x, (float)h.y, (float)h.z, (float)h.w);
}
__device__ __forceinline__ half4 f2h(float4 f) {
  half4 h;
  h.x = (h16)f.x; h.y = (h16)f.y; h.z = (h16)f.z; h.w = (h16)f.w;
  return h;
}

// ============ kW: wtab[c][n] = softmax_n(q_c . K_n), 513 blocks ============
__global__ __launch_bounds__(512) void kW(const float* __restrict__ Kmem,
                                          const float* __restrict__ cemb,
                                          float* __restrict__ wtab) {
  __shared__ float s_q[DK_];
  __shared__ float s_red[16];
  const int tid = threadIdx.x, c = blockIdx.x;
  if (tid < DK_) s_q[tid] = c ? cemb[c * DK_ + tid] : 0.f;
  __syncthreads();
  const int n = tid;
  const float4* kr = (const float4*)(Kmem + n * DK_);
  float acc = 0.f;
#pragma unroll
  for (int kk = 0; kk < DK_ / 4; ++kk) acc += dot4(kr[kk], *(const float4*)&s_q[kk * 4]);
  const int lane = tid & 63, wid = tid >> 6;
  float mx = acc;
  for (int off = 32; off; off >>= 1) mx = fmaxf(mx, __shfl_xor(mx, off, 64));
  if (lane == 0) s_red[wid] = mx;
  __syncthreads();
  float gmx = s_red[0];
#pragma unroll
  for (int i = 1; i < 8; ++i) gmx = fmaxf(gmx, s_red[i]);
  const float e = expf(acc - gmx);
  float sum = e;
  for (int off = 32; off; off >>= 1) sum += __shfl_xor(sum, off, 64);
  if (lane == 0) s_red[8 + wid] = sum;
  __syncthreads();
  float gs = 0.f;
#pragma unroll
  for (int i = 0; i < 8; ++i) gs += s_red[8 + i];
  wtab[c * N_ + n] = e / gs;
}

// ============ kG: etab/atab[id][d], 129 blocks x 8 ids =====================
__global__ __launch_bounds__(512) void kG(const float* __restrict__ iemb,
                                          const float* __restrict__ We,
                                          const float* __restrict__ be,
                                          const float* __restrict__ Wa,
                                          const float* __restrict__ ba,
                                          float* __restrict__ etab,
                                          float* __restrict__ atab) {
  __shared__ float s_v[8 * DV_];
  const int tid = threadIdx.x, bi = blockIdx.x;
  {
    const int j = tid >> 6, c4 = tid & 63;
    const int id = bi * 8 + j;
    float4 v = make_float4(0.f, 0.f, 0.f, 0.f);
    if (id >= 1 && id < NIID) v = ((const float4*)iemb)[(size_t)id * 64 + c4];
    *(float4*)&s_v[j * DV_ + c4 * 4] = v;
  }
  __syncthreads();
  const int gate = tid >> 8, d = tid & 255;
  const float4* wr = (const float4*)((gate ? Wa : We) + d * DV_);
  float acc[8];
#pragma unroll
  for (int j = 0; j < 8; ++j) acc[j] = 0.f;
  for (int kk = 0; kk < DV_ / 4; ++kk) {
    const float4 w4 = wr[kk];
#pragma unroll
    for (int j = 0; j < 8; ++j) acc[j] += dot4(w4, *(const float4*)&s_v[j * DV_ + kk * 4]);
  }
  const float bias = gate ? ba[d] : be[d];
#pragma unroll
  for (int j = 0; j < 8; ++j) {
    const int id = bi * 8 + j;
    if (id < NIID) {
      if (gate) atab[(size_t)id * DV_ + d] = tanhf(acc[j] + bias);
      else      etab[(size_t)id * DV_ + d] = 1.f / (1.f + expf(-(acc[j] + bias)));
    }
  }
}

// ============ kS: ring-staged sparse recurrence, 512 blocks x 1024 thr =====
#define ROWOP(mr, wsel)                                   \
  do {                                                    \
    const float w_ = (wsel);                              \
    racc.x = fmaf(w_, mr.x, racc.x);                      \
    racc.y = fmaf(w_, mr.y, racc.y);                      \
    racc.z = fmaf(w_, mr.z, racc.z);                      \
    racc.w = fmaf(w_, mr.w, racc.w);                      \
    mr.x = fmaf(-w_, fmaf(e4.x, mr.x, -a4.x), mr.x);      \
    mr.y = fmaf(-w_, fmaf(e4.y, mr.y, -a4.y), mr.y);      \
    mr.z = fmaf(-w_, fmaf(e4.z, mr.z, -a4.z), mr.z);      \
    mr.w = fmaf(-w_, fmaf(e4.w, mr.w, -a4.w), mr.w);      \
  } while (0)

#define GRP4(wq, A, B, C, D)                                              \
  do {                                                                    \
    const float gmx_ = fmaxf(fmaxf(wq.x, wq.y), fmaxf(wq.z, wq.w));       \
    if (__int_as_float(__builtin_amdgcn_readfirstlane(                    \
            __float_as_int(gmx_))) > EPSW) {                              \
      ROWOP(A, wq.x); ROWOP(B, wq.y); ROWOP(C, wq.z); ROWOP(D, wq.w);     \
    }                                                                     \
  } while (0)

__global__ __launch_bounds__(1024)
__attribute__((amdgpu_waves_per_eu(4, 4))) void kS(
    const int* __restrict__ concepts, const int* __restrict__ inter,
    const float* __restrict__ Vmem, const float* __restrict__ wtab,
    const float* __restrict__ etab, const float* __restrict__ atab,
    h16* __restrict__ rpart) {
  __shared__ float s_w[8][DV_];            // 8 KB: ring of 8 t-rows
  __shared__ float s_e[8][DV_];            // 8 KB
  __shared__ float s_a[8][DV_];            // 8 KB
  __shared__ float s_racc[2][4][16][DV_];  // 128 KB: double-buffered windows
  const int tid = threadIdx.x, bx = blockIdx.x;
  const int b = bx >> 1, ch = bx & 1;
  const int lane = tid & 63, wv = tid >> 6;  // 16 waves
  const int row0 = ch * 256 + __builtin_amdgcn_readfirstlane(wv * 16);
  float4 m0, m1, m2, m3, m4, m5, m6, m7, m8, m9, m10, m11, m12, m13, m14, m15;
  {
    const float4* vm4 = (const float4*)Vmem + (size_t)row0 * 64 + lane;
    m0 = vm4[0 * 64];   m1 = vm4[1 * 64];   m2 = vm4[2 * 64];   m3 = vm4[3 * 64];
    m4 = vm4[4 * 64];   m5 = vm4[5 * 64];   m6 = vm4[6 * 64];   m7 = vm4[7 * 64];
    m8 = vm4[8 * 64];   m9 = vm4[9 * 64];   m10 = vm4[10 * 64]; m11 = vm4[11 * 64];
    m12 = vm4[12 * 64]; m13 = vm4[13 * 64]; m14 = vm4[14 * 64]; m15 = vm4[15 * 64];
  }
  const int* cb = concepts + b * T_;
  const int* ib = inter + b * T_;
  const float4* wtab4 = (const float4*)wtab;
  const float4* etab4 = (const float4*)etab;
  const float4* atab4 = (const float4*)atab;
  h16* rp = rpart + (size_t)ch * NP_ * DV_ + (size_t)b * T_ * DV_;

  // stage 4 t-rows (w/e/a) into ring slots (tb..tb+3)&7; 768 threads from
  // toff, ONE float4 load each. arr and r are wave-uniform (192 = 3 x 64).
  auto stage4 = [&](int tb, int toff) {
    const int idx = tid - toff;
    if (idx >= 0 && idx < 768) {
      const int r = idx / 192, q = idx % 192;
      const int arr = q >> 6, c4 = q & 63;
      const int t = tb + r, sl = t & 7;
      if (arr == 0) {
        *(float4*)&s_w[sl][c4 * 4] = wtab4[(size_t)cb[t] * 128 + ch * 64 + c4];
      } else if (arr == 1) {
        *(float4*)&s_e[sl][c4 * 4] = etab4[(size_t)ib[t] * 64 + c4];
      } else {
        *(float4*)&s_a[sl][c4 * 4] = atab4[(size_t)ib[t] * 64 + c4];
      }
    }
  };

  stage4(0, 0);
  __syncthreads();

  for (int t0 = 0; t0 < T_; t0 += 4) {
    const int win = (t0 >> 2) & 1;
#pragma unroll 1  // CAP PRESSURE: one step's LDS reads live at a time
    for (int j = 0; j < 4; ++j) {
      const int sl = (t0 + j) & 7;
      const float* wrow = &s_w[sl][wv * 16];
      const float4 wq0 = *(const float4*)(wrow + 0);
      const float4 wq1 = *(const float4*)(wrow + 4);
      const float4 wq2 = *(const float4*)(wrow + 8);
      const float4 wq3 = *(const float4*)(wrow + 12);
      const float4 e4 = *(const float4*)&s_e[sl][lane * 4];
      const float4 a4 = *(const float4*)&s_a[sl][lane * 4];
      float4 racc = make_float4(0.f, 0.f, 0.f, 0.f);
      GRP4(wq0, m0, m1, m2, m3);
      GRP4(wq1, m4, m5, m6, m7);
      GRP4(wq2, m8, m9, m10, m11);
      GRP4(wq3, m12, m13, m14, m15);
      *(float4*)&s_racc[win][j][wv][lane * 4] = racc;
    }
    // waves 4-15: stage rows t0+4..t0+7 (slots disjoint from compute's).
    if (t0 + 4 < T_) stage4(t0 + 4, 256);
    // waves 0-3: drain PREVIOUS window (win^1) -> rows t0-4..t0-1.
    if (t0 > 0 && tid < 256) {
      const int j = tid >> 6, l = tid & 63;
      float4 acc = make_float4(0.f, 0.f, 0.f, 0.f);
#pragma unroll 4
      for (int w2 = 0; w2 < 16; ++w2) {
        const float4 v = *(const float4*)&s_racc[win ^ 1][j][w2][l * 4];
        acc.x += v.x; acc.y += v.y; acc.z += v.z; acc.w += v.w;
      }
      *(half4*)(rp + (size_t)(t0 - 4 + j) * DV_ + l * 4) = f2h(acc);
    }
    __syncthreads();
  }
  // final drain: last window (t0 = 508 -> win 1), rows 508..511.
  if (tid < 256) {
    const int buf = ((T_ - 4) >> 2) & 1;
    const int j = tid >> 6, l = tid & 63;
    float4 acc = make_float4(0.f, 0.f, 0.f, 0.f);
#pragma unroll 4
    for (int w2 = 0; w2 < 16; ++w2) {
      const float4 v = *(const float4*)&s_racc[buf][j][w2][l * 4];
      acc.x += v.x; acc.y += v.y; acc.z += v.z; acc.w += v.w;
    }
    *(half4*)(rp + (size_t)(T_ - 4 + j) * DV_ + l * 4) = f2h(acc);
  }
}

// ============ kM: MLP head, 2048 blocks x 1024 thr, lane=p (R26-exact) =====
#define MP_ 64
#define SF_ 321  // s_f dword stride (odd -> bank-conflict-free b32)
#define SH_ 65   // s_h1 dword stride (odd)
#define SR_ 17   // s_red dword stride (odd)
__global__ __launch_bounds__(1024) void kM(const int* __restrict__ concepts,
                                           const float* __restrict__ cemb,
                                           const h16* __restrict__ rpart,
                                           const float* __restrict__ W1,
                                           const float* __restrict__ b1,
                                           const float* __restrict__ W2,
                                           const float* __restrict__ b2,
                                           const float* __restrict__ W3,
                                           const float* __restrict__ b3,
                                           float* __restrict__ out) {
  __shared__ float s_f[MP_][SF_];   // 82.2 KB: f = [r(256) | q(64)] fp32
  __shared__ float s_h1[MP_][SH_];  // 16.6 KB
  __shared__ float s_red[MP_][SR_]; // 4.4 KB
  __shared__ int s_c[MP_];
  const int tid = threadIdx.x, g = blockIdx.x;
  const int lane = tid & 63, wv = tid >> 6;  // 16 waves; lane = sample p
  if (tid < MP_) s_c[tid] = concepts[g * MP_ + tid];
  __syncthreads();
  {
    const half4* p0 = (const half4*)rpart;
    const half4* p1 = p0 + (size_t)NP_ * 64;
#pragma unroll
    for (int i = 0; i < 4; ++i) {
      const int idx = tid + i * 1024, p = idx >> 6, c4 = idx & 63;
      const size_t off = (size_t)(g * MP_ + p) * 64 + c4;
      const float4 v0 = h2f(p0[off]);
      const float4 v1 = h2f(p1[off]);
      s_f[p][c4 * 4 + 0] = v0.x + v1.x;
      s_f[p][c4 * 4 + 1] = v0.y + v1.y;
      s_f[p][c4 * 4 + 2] = v0.z + v1.z;
      s_f[p][c4 * 4 + 3] = v0.w + v1.w;
    }
    const float4* ce4 = (const float4*)cemb;
    const float4 z = make_float4(0.f, 0.f, 0.f, 0.f);
    const int p = tid >> 4, k4 = tid & 15;
    const int c = s_c[p];
    const float4 q = c ? ce4[c * 16 + k4] : z;
    s_f[p][DV_ + k4 * 4 + 0] = q.x;
    s_f[p][DV_ + k4 * 4 + 1] = q.y;
    s_f[p][DV_ + k4 * 4 + 2] = q.z;
    s_f[p][DV_ + k4 * 4 + 3] = q.w;
  }
  __syncthreads();
  // ---- layer 1: h1[p][j] = relu(b1[j] + sum_k W1[j][k] f[p][k]) ----
  {
    const int j0 = wv * 4;  // wave-uniform
    const float* W1r0 = W1 + (size_t)(j0 + 0) * 320;
    const float* W1r1 = W1 + (size_t)(j0 + 1) * 320;
    const float* W1r2 = W1 + (size_t)(j0 + 2) * 320;
    const float* W1r3 = W1 + (size_t)(j0 + 3) * 320;
    float a0 = b1[j0 + 0], a1 = b1[j0 + 1], a2 = b1[j0 + 2], a3 = b1[j0 + 3];
#pragma unroll 1
    for (int k4 = 0; k4 < 80; ++k4) {
      const float4 w0 = *(const float4*)(W1r0 + k4 * 4);  // s_load (uniform)
      const float4 w1 = *(const float4*)(W1r1 + k4 * 4);
      const float4 w2 = *(const float4*)(W1r2 + k4 * 4);
      const float4 w3 = *(const float4*)(W1r3 + k4 * 4);
      const float f0 = s_f[lane][k4 * 4 + 0];  // conflict-free b32
      const float f1 = s_f[lane][k4 * 4 + 1];
      const float f2 = s_f[lane][k4 * 4 + 2];
      const float f3 = s_f[lane][k4 * 4 + 3];
      a0 = fmaf(w0.x, f0, fmaf(w0.y, f1, fmaf(w0.z, f2, fmaf(w0.w, f3, a0))));
      a1 = fmaf(w1.x, f0, fmaf(w1.y, f1, fmaf(w1.z, f2, fmaf(w1.w, f3, a1))));
      a2 = fmaf(w2.x, f0, fmaf(w2.y, f1, fmaf(w2.z, f2, fmaf(w2.w, f3, a2))));
      a3 = fmaf(w3.x, f0, fmaf(w3.y, f1, fmaf(w3.z, f2, fmaf(w3.w, f3, a3))));
    }
    s_h1[lane][j0 + 0] = fmaxf(a0, 0.f);
    s_h1[lane][j0 + 1] = fmaxf(a1, 0.f);
    s_h1[lane][j0 + 2] = fmaxf(a2, 0.f);
    s_h1[lane][j0 + 3] = fmaxf(a3, 0.f);
  }
  __syncthreads();
  // ---- layer 2 + W3 partial: wave handles j2 = 4wv..4wv+3 ----
  {
    const int j0 = wv * 4;
    const float* W2r0 = W2 + (size_t)(j0 + 0) * 64;
    const float* W2r1 = W2 + (size_t)(j0 + 1) * 64;
    const float* W2r2 = W2 + (size_t)(j0 + 2) * 64;
    const float* W2r3 = W2 + (size_t)(j0 + 3) * 64;
    float a0 = b2[j0 + 0], a1 = b2[j0 + 1], a2 = b2[j0 + 2], a3 = b2[j0 + 3];
#pragma unroll 1
    for (int k4 = 0; k4 < 16; ++k4) {
      const float4 w0 = *(const float4*)(W2r0 + k4 * 4);
      const float4 w1 = *(const float4*)(W2r1 + k4 * 4);
      const float4 w2 = *(const float4*)(W2r2 + k4 * 4);
      const float4 w3 = *(const float4*)(W2r3 + k4 * 4);
      const float h0 = s_h1[lane][k4 * 4 + 0];
      const float h1v = s_h1[lane][k4 * 4 + 1];
      const float h2v = s_h1[lane][k4 * 4 + 2];
      const float h3 = s_h1[lane][k4 * 4 + 3];
      a0 = fmaf(w0.x, h0, fmaf(w0.y, h1v, fmaf(w0.z, h2v, fmaf(w0.w, h3, a0))));
      a1 = fmaf(w1.x, h0, fmaf(w1.y, h1v, fmaf(w1.z, h2v, fmaf(w1.w, h3, a1))));
      a2 = fmaf(w2.x, h0, fmaf(w2.y, h1v, fmaf(w2.z, h2v, fmaf(w2.w, h3, a2))));
      a3 = fmaf(w3.x, h0, fmaf(w3.y, h1v, fmaf(w3.z, h2v, fmaf(w3.w, h3, a3))));
    }
    const float p3 = fmaxf(a0, 0.f) * W3[j0 + 0] + fmaxf(a1, 0.f) * W3[j0 + 1] +
                     fmaxf(a2, 0.f) * W3[j0 + 2] + fmaxf(a3, 0.f) * W3[j0 + 3];
    s_red[lane][wv] = p3;
  }
  __syncthreads();
  if (wv == 0) {
    float s = b3[0];
#pragma unroll
    for (int w = 0; w < 16; ++w) s += s_red[lane][w];
    out[g * MP_ + lane] = 1.f / (1.f + expf(-s));
  }
}

extern "C" void kernel_launch(void* const* d_in, const int* in_sizes, int n_in,
                              void* d_out, int out_size, void* d_ws, size_t ws_size,
                              hipStream_t stream) {
  const int* concepts = (const int*)d_in[0];
  const int* interactions = (const int*)d_in[1];
  const float* Kmem = (const float*)d_in[2];
  const float* Vmem = (const float*)d_in[3];
  const float* cemb = (const float*)d_in[4];
  const float* iemb = (const float*)d_in[5];
  const float* We = (const float*)d_in[6];
  const float* be = (const float*)d_in[7];
  const float* Wa = (const float*)d_in[8];
  const float* ba = (const float*)d_in[9];
  const float* W1 = (const float*)d_in[10];
  const float* b1 = (const float*)d_in[11];
  const float* W2 = (const float*)d_in[12];
  const float* b2 = (const float*)d_in[13];
  const float* W3 = (const float*)d_in[14];
  const float* b3 = (const float*)d_in[15];
  float* out = (float*)d_out;

  const size_t sz_w = (size_t)NCID * N_ * 4;
  const size_t sz_e = (size_t)NIID * DV_ * 4;
  float* wtab = (float*)d_ws;
  float* etab = (float*)((char*)d_ws + sz_w);
  float* atab = (float*)((char*)d_ws + sz_w + sz_e);
  h16* rpart = (h16*)((char*)d_ws + sz_w + 2 * sz_e);  // 2 x 64 MiB

  kW<<<dim3(NCID), dim3(512), 0, stream>>>(Kmem, cemb, wtab);
  kG<<<dim3((NIID + 7) / 8), dim3(512), 0, stream>>>(iemb, We, be, Wa, ba, etab, atab);
  kS<<<dim3(B_ * 2), dim3(1024), 0, stream>>>(concepts, interactions, Vmem,
                                              wtab, etab, atab, rpart);
  kM<<<dim3(NP_ / MP_), dim3(1024), 0, stream>>>(concepts, cemb, rpart,
                                                 W1, b1, W2, b2, W3, b3, out);
}

// Round 14
// 1034.866 us; speedup vs baseline: 1.4102x; 1.2155x over previous
//
#include <hip/hip_runtime.h>

// DKVMN forward, round 28 — kM: scalarize weight reads + pipeline SMEM.
// R27 post-mortem: ring neutral (897->891); kS is VALU-issue bound (~600 us
// of 890) — leave it. Target = rest (367 us, kM ~290). Diagnosis: kM's
// j0 = wv*4 was never readfirstlane'd; LLVM treats tid>>6 as divergent, so
// W1/W2 row reads are per-lane VMEM (L2-hit ~200 cyc) and unroll-1
// serializes layer-1 on that latency (80 iters x 200 cyc, 4 waves/SIMD).
// R28 (kM only, kS/kW/kG byte-identical to R27 green):
//   1) readfirstlane(j0) -> weights provably wave-uniform -> s_load (SMEM);
//   2) #pragma unroll 4 layer-1 / full unroll layer-2 -> SMEM pipelined;
//   3) amdgpu_waves_per_eu(4,4) -> 128-VGPR budget for the unroll (R19).
// Accumulation order unchanged -> bit-identical output.
//   kW: wtab[513][512] fp32   kG: etab/atab[1025][256] fp32   (3.2 MB, hot)
//   kS: ring-staged, s_racc dbuf, 1 barrier/4 steps, EPSW 1e-6 (891 us green)
//   kM: lane=p, SGPR weights, odd-stride b32 LDS.
// ws = 3.2 MB + 128 MiB.

#define B_ 256
#define T_ 512
#define N_ 512
#define DK_ 64
#define DV_ 256
#define S_ 64
#define NP_ (B_ * T_)
#define NCID 513
#define NIID 1025
#define EPSW 1e-6f

typedef _Float16 h16;
typedef __attribute__((ext_vector_type(4))) _Float16 half4;

__device__ __forceinline__ float dot4(float4 a, float4 b) {
  return a.x * b.x + a.y * b.y + a.z * b.z + a.w * b.w;
}
__device__ __forceinline__ float4 h2f(half4 h) {
  return make_float4((float)h.x, (float)h.y, (float)h.z, (float)h.w);
}
__device__ __forceinline__ half4 f2h(float4 f) {
  half4 h;
  h.x = (h16)f.x; h.y = (h16)f.y; h.z = (h16)f.z; h.w = (h16)f.w;
  return h;
}

// ============ kW: wtab[c][n] = softmax_n(q_c . K_n), 513 blocks ============
__global__ __launch_bounds__(512) void kW(const float* __restrict__ Kmem,
                                          const float* __restrict__ cemb,
                                          float* __restrict__ wtab) {
  __shared__ float s_q[DK_];
  __shared__ float s_red[16];
  const int tid = threadIdx.x, c = blockIdx.x;
  if (tid < DK_) s_q[tid] = c ? cemb[c * DK_ + tid] : 0.f;
  __syncthreads();
  const int n = tid;
  const float4* kr = (const float4*)(Kmem + n * DK_);
  float acc = 0.f;
#pragma unroll
  for (int kk = 0; kk < DK_ / 4; ++kk) acc += dot4(kr[kk], *(const float4*)&s_q[kk * 4]);
  const int lane = tid & 63, wid = tid >> 6;
  float mx = acc;
  for (int off = 32; off; off >>= 1) mx = fmaxf(mx, __shfl_xor(mx, off, 64));
  if (lane == 0) s_red[wid] = mx;
  __syncthreads();
  float gmx = s_red[0];
#pragma unroll
  for (int i = 1; i < 8; ++i) gmx = fmaxf(gmx, s_red[i]);
  const float e = expf(acc - gmx);
  float sum = e;
  for (int off = 32; off; off >>= 1) sum += __shfl_xor(sum, off, 64);
  if (lane == 0) s_red[8 + wid] = sum;
  __syncthreads();
  float gs = 0.f;
#pragma unroll
  for (int i = 0; i < 8; ++i) gs += s_red[8 + i];
  wtab[c * N_ + n] = e / gs;
}

// ============ kG: etab/atab[id][d], 129 blocks x 8 ids =====================
__global__ __launch_bounds__(512) void kG(const float* __restrict__ iemb,
                                          const float* __restrict__ We,
                                          const float* __restrict__ be,
                                          const float* __restrict__ Wa,
                                          const float* __restrict__ ba,
                                          float* __restrict__ etab,
                                          float* __restrict__ atab) {
  __shared__ float s_v[8 * DV_];
  const int tid = threadIdx.x, bi = blockIdx.x;
  {
    const int j = tid >> 6, c4 = tid & 63;
    const int id = bi * 8 + j;
    float4 v = make_float4(0.f, 0.f, 0.f, 0.f);
    if (id >= 1 && id < NIID) v = ((const float4*)iemb)[(size_t)id * 64 + c4];
    *(float4*)&s_v[j * DV_ + c4 * 4] = v;
  }
  __syncthreads();
  const int gate = tid >> 8, d = tid & 255;
  const float4* wr = (const float4*)((gate ? Wa : We) + d * DV_);
  float acc[8];
#pragma unroll
  for (int j = 0; j < 8; ++j) acc[j] = 0.f;
  for (int kk = 0; kk < DV_ / 4; ++kk) {
    const float4 w4 = wr[kk];
#pragma unroll
    for (int j = 0; j < 8; ++j) acc[j] += dot4(w4, *(const float4*)&s_v[j * DV_ + kk * 4]);
  }
  const float bias = gate ? ba[d] : be[d];
#pragma unroll
  for (int j = 0; j < 8; ++j) {
    const int id = bi * 8 + j;
    if (id < NIID) {
      if (gate) atab[(size_t)id * DV_ + d] = tanhf(acc[j] + bias);
      else      etab[(size_t)id * DV_ + d] = 1.f / (1.f + expf(-(acc[j] + bias)));
    }
  }
}

// ============ kS: ring-staged sparse recurrence, 512 blocks x 1024 thr =====
// R27-exact (891 us green).
#define ROWOP(mr, wsel)                                   \
  do {                                                    \
    const float w_ = (wsel);                              \
    racc.x = fmaf(w_, mr.x, racc.x);                      \
    racc.y = fmaf(w_, mr.y, racc.y);                      \
    racc.z = fmaf(w_, mr.z, racc.z);                      \
    racc.w = fmaf(w_, mr.w, racc.w);                      \
    mr.x = fmaf(-w_, fmaf(e4.x, mr.x, -a4.x), mr.x);      \
    mr.y = fmaf(-w_, fmaf(e4.y, mr.y, -a4.y), mr.y);      \
    mr.z = fmaf(-w_, fmaf(e4.z, mr.z, -a4.z), mr.z);      \
    mr.w = fmaf(-w_, fmaf(e4.w, mr.w, -a4.w), mr.w);      \
  } while (0)

#define GRP4(wq, A, B, C, D)                                              \
  do {                                                                    \
    const float gmx_ = fmaxf(fmaxf(wq.x, wq.y), fmaxf(wq.z, wq.w));       \
    if (__int_as_float(__builtin_amdgcn_readfirstlane(                    \
            __float_as_int(gmx_))) > EPSW) {                              \
      ROWOP(A, wq.x); ROWOP(B, wq.y); ROWOP(C, wq.z); ROWOP(D, wq.w);     \
    }                                                                     \
  } while (0)

__global__ __launch_bounds__(1024)
__attribute__((amdgpu_waves_per_eu(4, 4))) void kS(
    const int* __restrict__ concepts, const int* __restrict__ inter,
    const float* __restrict__ Vmem, const float* __restrict__ wtab,
    const float* __restrict__ etab, const float* __restrict__ atab,
    h16* __restrict__ rpart) {
  __shared__ float s_w[8][DV_];            // 8 KB: ring of 8 t-rows
  __shared__ float s_e[8][DV_];            // 8 KB
  __shared__ float s_a[8][DV_];            // 8 KB
  __shared__ float s_racc[2][4][16][DV_];  // 128 KB: double-buffered windows
  const int tid = threadIdx.x, bx = blockIdx.x;
  const int b = bx >> 1, ch = bx & 1;
  const int lane = tid & 63, wv = tid >> 6;  // 16 waves
  const int row0 = ch * 256 + __builtin_amdgcn_readfirstlane(wv * 16);
  float4 m0, m1, m2, m3, m4, m5, m6, m7, m8, m9, m10, m11, m12, m13, m14, m15;
  {
    const float4* vm4 = (const float4*)Vmem + (size_t)row0 * 64 + lane;
    m0 = vm4[0 * 64];   m1 = vm4[1 * 64];   m2 = vm4[2 * 64];   m3 = vm4[3 * 64];
    m4 = vm4[4 * 64];   m5 = vm4[5 * 64];   m6 = vm4[6 * 64];   m7 = vm4[7 * 64];
    m8 = vm4[8 * 64];   m9 = vm4[9 * 64];   m10 = vm4[10 * 64]; m11 = vm4[11 * 64];
    m12 = vm4[12 * 64]; m13 = vm4[13 * 64]; m14 = vm4[14 * 64]; m15 = vm4[15 * 64];
  }
  const int* cb = concepts + b * T_;
  const int* ib = inter + b * T_;
  const float4* wtab4 = (const float4*)wtab;
  const float4* etab4 = (const float4*)etab;
  const float4* atab4 = (const float4*)atab;
  h16* rp = rpart + (size_t)ch * NP_ * DV_ + (size_t)b * T_ * DV_;

  auto stage4 = [&](int tb, int toff) {
    const int idx = tid - toff;
    if (idx >= 0 && idx < 768) {
      const int r = idx / 192, q = idx % 192;
      const int arr = q >> 6, c4 = q & 63;
      const int t = tb + r, sl = t & 7;
      if (arr == 0) {
        *(float4*)&s_w[sl][c4 * 4] = wtab4[(size_t)cb[t] * 128 + ch * 64 + c4];
      } else if (arr == 1) {
        *(float4*)&s_e[sl][c4 * 4] = etab4[(size_t)ib[t] * 64 + c4];
      } else {
        *(float4*)&s_a[sl][c4 * 4] = atab4[(size_t)ib[t] * 64 + c4];
      }
    }
  };

  stage4(0, 0);
  __syncthreads();

  for (int t0 = 0; t0 < T_; t0 += 4) {
    const int win = (t0 >> 2) & 1;
#pragma unroll 1  // CAP PRESSURE: one step's LDS reads live at a time
    for (int j = 0; j < 4; ++j) {
      const int sl = (t0 + j) & 7;
      const float* wrow = &s_w[sl][wv * 16];
      const float4 wq0 = *(const float4*)(wrow + 0);
      const float4 wq1 = *(const float4*)(wrow + 4);
      const float4 wq2 = *(const float4*)(wrow + 8);
      const float4 wq3 = *(const float4*)(wrow + 12);
      const float4 e4 = *(const float4*)&s_e[sl][lane * 4];
      const float4 a4 = *(const float4*)&s_a[sl][lane * 4];
      float4 racc = make_float4(0.f, 0.f, 0.f, 0.f);
      GRP4(wq0, m0, m1, m2, m3);
      GRP4(wq1, m4, m5, m6, m7);
      GRP4(wq2, m8, m9, m10, m11);
      GRP4(wq3, m12, m13, m14, m15);
      *(float4*)&s_racc[win][j][wv][lane * 4] = racc;
    }
    if (t0 + 4 < T_) stage4(t0 + 4, 256);
    if (t0 > 0 && tid < 256) {
      const int j = tid >> 6, l = tid & 63;
      float4 acc = make_float4(0.f, 0.f, 0.f, 0.f);
#pragma unroll 4
      for (int w2 = 0; w2 < 16; ++w2) {
        const float4 v = *(const float4*)&s_racc[win ^ 1][j][w2][l * 4];
        acc.x += v.x; acc.y += v.y; acc.z += v.z; acc.w += v.w;
      }
      *(half4*)(rp + (size_t)(t0 - 4 + j) * DV_ + l * 4) = f2h(acc);
    }
    __syncthreads();
  }
  if (tid < 256) {
    const int buf = ((T_ - 4) >> 2) & 1;
    const int j = tid >> 6, l = tid & 63;
    float4 acc = make_float4(0.f, 0.f, 0.f, 0.f);
#pragma unroll 4
    for (int w2 = 0; w2 < 16; ++w2) {
      const float4 v = *(const float4*)&s_racc[buf][j][w2][l * 4];
      acc.x += v.x; acc.y += v.y; acc.z += v.z; acc.w += v.w;
    }
    *(half4*)(rp + (size_t)(T_ - 4 + j) * DV_ + l * 4) = f2h(acc);
  }
}

// ============ kM: MLP head, 2048 blocks x 1024 thr, lane=p =================
// R28: readfirstlane(j0) forces W1/W2/b reads onto the scalar (SMEM) pipe;
// unroll-4 keeps 4 iterations' s_loads in flight; waves_per_eu(4,4) gives
// the unroll a 128-VGPR budget (1 block/CU anyway at 103 KB LDS).
#define MP_ 64
#define SF_ 321  // s_f dword stride (odd -> bank-conflict-free b32)
#define SH_ 65   // s_h1 dword stride (odd)
#define SR_ 17   // s_red dword stride (odd)
__global__ __launch_bounds__(1024)
__attribute__((amdgpu_waves_per_eu(4, 4))) void kM(
    const int* __restrict__ concepts, const float* __restrict__ cemb,
    const h16* __restrict__ rpart, const float* __restrict__ W1,
    const float* __restrict__ b1, const float* __restrict__ W2,
    const float* __restrict__ b2, const float* __restrict__ W3,
    const float* __restrict__ b3, float* __restrict__ out) {
  __shared__ float s_f[MP_][SF_];   // 82.2 KB: f = [r(256) | q(64)] fp32
  __shared__ float s_h1[MP_][SH_];  // 16.6 KB
  __shared__ float s_red[MP_][SR_]; // 4.4 KB
  __shared__ int s_c[MP_];
  const int tid = threadIdx.x, g = blockIdx.x;
  const int lane = tid & 63, wv = tid >> 6;  // 16 waves; lane = sample p
  if (tid < MP_) s_c[tid] = concepts[g * MP_ + tid];
  __syncthreads();
  {
    const half4* p0 = (const half4*)rpart;
    const half4* p1 = p0 + (size_t)NP_ * 64;
#pragma unroll
    for (int i = 0; i < 4; ++i) {
      const int idx = tid + i * 1024, p = idx >> 6, c4 = idx & 63;
      const size_t off = (size_t)(g * MP_ + p) * 64 + c4;
      const float4 v0 = h2f(p0[off]);
      const float4 v1 = h2f(p1[off]);
      s_f[p][c4 * 4 + 0] = v0.x + v1.x;
      s_f[p][c4 * 4 + 1] = v0.y + v1.y;
      s_f[p][c4 * 4 + 2] = v0.z + v1.z;
      s_f[p][c4 * 4 + 3] = v0.w + v1.w;
    }
    const float4* ce4 = (const float4*)cemb;
    const float4 z = make_float4(0.f, 0.f, 0.f, 0.f);
    const int p = tid >> 4, k4 = tid & 15;
    const int c = s_c[p];
    const float4 q = c ? ce4[c * 16 + k4] : z;
    s_f[p][DV_ + k4 * 4 + 0] = q.x;
    s_f[p][DV_ + k4 * 4 + 1] = q.y;
    s_f[p][DV_ + k4 * 4 + 2] = q.z;
    s_f[p][DV_ + k4 * 4 + 3] = q.w;
  }
  __syncthreads();
  // ---- layer 1: h1[p][j] = relu(b1[j] + sum_k W1[j][k] f[p][k]) ----
  {
    const int j0 = __builtin_amdgcn_readfirstlane(wv * 4);  // FORCE scalar
    const float* W1r0 = W1 + (size_t)(j0 + 0) * 320;
    const float* W1r1 = W1 + (size_t)(j0 + 1) * 320;
    const float* W1r2 = W1 + (size_t)(j0 + 2) * 320;
    const float* W1r3 = W1 + (size_t)(j0 + 3) * 320;
    float a0 = b1[j0 + 0], a1 = b1[j0 + 1], a2 = b1[j0 + 2], a3 = b1[j0 + 3];
#pragma unroll 4
    for (int k4 = 0; k4 < 80; ++k4) {
      const float4 w0 = *(const float4*)(W1r0 + k4 * 4);  // s_load (uniform)
      const float4 w1 = *(const float4*)(W1r1 + k4 * 4);
      const float4 w2 = *(const float4*)(W1r2 + k4 * 4);
      const float4 w3 = *(const float4*)(W1r3 + k4 * 4);
      const float f0 = s_f[lane][k4 * 4 + 0];  // conflict-free b32
      const float f1 = s_f[lane][k4 * 4 + 1];
      const float f2 = s_f[lane][k4 * 4 + 2];
      const float f3 = s_f[lane][k4 * 4 + 3];
      a0 = fmaf(w0.x, f0, fmaf(w0.y, f1, fmaf(w0.z, f2, fmaf(w0.w, f3, a0))));
      a1 = fmaf(w1.x, f0, fmaf(w1.y, f1, fmaf(w1.z, f2, fmaf(w1.w, f3, a1))));
      a2 = fmaf(w2.x, f0, fmaf(w2.y, f1, fmaf(w2.z, f2, fmaf(w2.w, f3, a2))));
      a3 = fmaf(w3.x, f0, fmaf(w3.y, f1, fmaf(w3.z, f2, fmaf(w3.w, f3, a3))));
    }
    s_h1[lane][j0 + 0] = fmaxf(a0, 0.f);
    s_h1[lane][j0 + 1] = fmaxf(a1, 0.f);
    s_h1[lane][j0 + 2] = fmaxf(a2, 0.f);
    s_h1[lane][j0 + 3] = fmaxf(a3, 0.f);
  }
  __syncthreads();
  // ---- layer 2 + W3 partial: wave handles j2 = 4wv..4wv+3 ----
  {
    const int j0 = __builtin_amdgcn_readfirstlane(wv * 4);  // FORCE scalar
    const float* W2r0 = W2 + (size_t)(j0 + 0) * 64;
    const float* W2r1 = W2 + (size_t)(j0 + 1) * 64;
    const float* W2r2 = W2 + (size_t)(j0 + 2) * 64;
    const float* W2r3 = W2 + (size_t)(j0 + 3) * 64;
    float a0 = b2[j0 + 0], a1 = b2[j0 + 1], a2 = b2[j0 + 2], a3 = b2[j0 + 3];
#pragma unroll 4
    for (int k4 = 0; k4 < 16; ++k4) {
      const float4 w0 = *(const float4*)(W2r0 + k4 * 4);
      const float4 w1 = *(const float4*)(W2r1 + k4 * 4);
      const float4 w2 = *(const float4*)(W2r2 + k4 * 4);
      const float4 w3 = *(const float4*)(W2r3 + k4 * 4);
      const float h0 = s_h1[lane][k4 * 4 + 0];
      const float h1v = s_h1[lane][k4 * 4 + 1];
      const float h2v = s_h1[lane][k4 * 4 + 2];
      const float h3 = s_h1[lane][k4 * 4 + 3];
      a0 = fmaf(w0.x, h0, fmaf(w0.y, h1v, fmaf(w0.z, h2v, fmaf(w0.w, h3, a0))));
      a1 = fmaf(w1.x, h0, fmaf(w1.y, h1v, fmaf(w1.z, h2v, fmaf(w1.w, h3, a1))));
      a2 = fmaf(w2.x, h0, fmaf(w2.y, h1v, fmaf(w2.z, h2v, fmaf(w2.w, h3, a2))));
      a3 = fmaf(w3.x, h0, fmaf(w3.y, h1v, fmaf(w3.z, h2v, fmaf(w3.w, h3, a3))));
    }
    const float p3 = fmaxf(a0, 0.f) * W3[j0 + 0] + fmaxf(a1, 0.f) * W3[j0 + 1] +
                     fmaxf(a2, 0.f) * W3[j0 + 2] + fmaxf(a3, 0.f) * W3[j0 + 3];
    s_red[lane][wv] = p3;
  }
  __syncthreads();
  if (wv == 0) {
    float s = b3[0];
#pragma unroll
    for (int w = 0; w < 16; ++w) s += s_red[lane][w];
    out[g * MP_ + lane] = 1.f / (1.f + expf(-s));
  }
}

extern "C" void kernel_launch(void* const* d_in, const int* in_sizes, int n_in,
                              void* d_out, int out_size, void* d_ws, size_t ws_size,
                              hipStream_t stream) {
  const int* concepts = (const int*)d_in[0];
  const int* interactions = (const int*)d_in[1];
  const float* Kmem = (const float*)d_in[2];
  const float* Vmem = (const float*)d_in[3];
  const float* cemb = (const float*)d_in[4];
  const float* iemb = (const float*)d_in[5];
  const float* We = (const float*)d_in[6];
  const float* be = (const float*)d_in[7];
  const float* Wa = (const float*)d_in[8];
  const float* ba = (const float*)d_in[9];
  const float* W1 = (const float*)d_in[10];
  const float* b1 = (const float*)d_in[11];
  const float* W2 = (const float*)d_in[12];
  const float* b2 = (const float*)d_in[13];
  const float* W3 = (const float*)d_in[14];
  const float* b3 = (const float*)d_in[15];
  float* out = (float*)d_out;

  const size_t sz_w = (size_t)NCID * N_ * 4;
  const size_t sz_e = (size_t)NIID * DV_ * 4;
  float* wtab = (float*)d_ws;
  float* etab = (float*)((char*)d_ws + sz_w);
  float* atab = (float*)((char*)d_ws + sz_w + sz_e);
  h16* rpart = (h16*)((char*)d_ws + sz_w + 2 * sz_e);  // 2 x 64 MiB

  kW<<<dim3(NCID), dim3(512), 0, stream>>>(Kmem, cemb, wtab);
  kG<<<dim3((NIID + 7) / 8), dim3(512), 0, stream>>>(iemb, We, be, Wa, ba, etab, atab);
  kS<<<dim3(B_ * 2), dim3(1024), 0, stream>>>(concepts, interactions, Vmem,
                                              wtab, etab, atab, rpart);
  kM<<<dim3(NP_ / MP_), dim3(1024), 0, stream>>>(concepts, cemb, rpart,
                                                 W1, b1, W2, b2, W3, b3, out);
}

// Round 15
// 965.568 us; speedup vs baseline: 1.5114x; 1.0718x over previous
//
#include <hip/hip_runtime.h>

// DKVMN forward, round 29 — hot-group mask precomputed in kW.
// R28 green: total 1035, kS 892 (86%). kS VALU ~600 us decomposes as hot-FMA
// ~260 + SKIP-CHECK OVERHEAD ~137 (4 always-read b128 w-rows + 12 fmax +
// 4 rfl/cmp per wave-step) + imbalance. The skip predicate depends only on
// (c, group) -> compute ONCE in kW: per-wave 64-bit ballot(w>EPSW) compressed
// to uint16 group mask, hmask[513][8] (16 KB, ws slack; rpart shifted 16 KB).
// kS stages 16 B mask/t-row (1 extra uint4 in stage4); step body = 1 scalar
// mask read + 4 scalar bit tests; w-row b128 reads move INSIDE hot branches
// (avg 1.56 instead of 4); e4/a4 skipped when nibble==0 (~14%). Skip set is
// BIT-IDENTICAL to R28 (same predicate) -> output unchanged.
// kM/kG byte-identical to R28; kS ring/drain/anti-spill invariants kept.
//   kW: wtab[513][512] fp32 + hmask[513][8] u16   kG: etab/atab fp32
//   kS: ring-staged, s_racc dbuf, 1 barrier/4 steps, mask-driven skip.
//   kM: lane=p, readfirstlane-scalar weights, odd-stride b32 LDS.
// ws = 3.2 MB + 16 KB + 128 MiB (of ~256 MB).

#define B_ 256
#define T_ 512
#define N_ 512
#define DK_ 64
#define DV_ 256
#define S_ 64
#define NP_ (B_ * T_)
#define NCID 513
#define NIID 1025
#define EPSW 1e-6f

typedef _Float16 h16;
typedef __attribute__((ext_vector_type(4))) _Float16 half4;
typedef unsigned int u32;
typedef unsigned short u16;

__device__ __forceinline__ float dot4(float4 a, float4 b) {
  return a.x * b.x + a.y * b.y + a.z * b.z + a.w * b.w;
}
__device__ __forceinline__ float4 h2f(half4 h) {
  return make_float4((float)h.x, (float)h.y, (float)h.z, (float)h.w);
}
__device__ __forceinline__ half4 f2h(float4 f) {
  half4 h;
  h.x = (h16)f.x; h.y = (h16)f.y; h.z = (h16)f.z; h.w = (h16)f.w;
  return h;
}

// ============ kW: wtab[c][n] + hmask[c][wave], 513 blocks ==================
__global__ __launch_bounds__(512) void kW(const float* __restrict__ Kmem,
                                          const float* __restrict__ cemb,
                                          float* __restrict__ wtab,
                                          u16* __restrict__ hmask) {
  __shared__ float s_q[DK_];
  __shared__ float s_red[16];
  const int tid = threadIdx.x, c = blockIdx.x;
  if (tid < DK_) s_q[tid] = c ? cemb[c * DK_ + tid] : 0.f;
  __syncthreads();
  const int n = tid;
  const float4* kr = (const float4*)(Kmem + n * DK_);
  float acc = 0.f;
#pragma unroll
  for (int kk = 0; kk < DK_ / 4; ++kk) acc += dot4(kr[kk], *(const float4*)&s_q[kk * 4]);
  const int lane = tid & 63, wid = tid >> 6;
  float mx = acc;
  for (int off = 32; off; off >>= 1) mx = fmaxf(mx, __shfl_xor(mx, off, 64));
  if (lane == 0) s_red[wid] = mx;
  __syncthreads();
  float gmx = s_red[0];
#pragma unroll
  for (int i = 1; i < 8; ++i) gmx = fmaxf(gmx, s_red[i]);
  const float e = expf(acc - gmx);
  float sum = e;
  for (int off = 32; off; off >>= 1) sum += __shfl_xor(sum, off, 64);
  if (lane == 0) s_red[8 + wid] = sum;
  __syncthreads();
  float gs = 0.f;
#pragma unroll
  for (int i = 0; i < 8; ++i) gs += s_red[8 + i];
  const float w = e / gs;
  wtab[c * N_ + n] = w;
  // hot-group mask: bit i of hmask[c*8+wid] = OR over 4 rows of (w > EPSW).
  const unsigned long long bal = __ballot(w > EPSW);
  if (lane == 0) {
    u16 mm = 0;
#pragma unroll
    for (int i = 0; i < 16; ++i)
      if ((bal >> (4 * i)) & 0xFull) mm |= (u16)(1u << i);
    hmask[c * 8 + wid] = mm;
  }
}

// ============ kG: etab/atab[id][d], 129 blocks x 8 ids =====================
__global__ __launch_bounds__(512) void kG(const float* __restrict__ iemb,
                                          const float* __restrict__ We,
                                          const float* __restrict__ be,
                                          const float* __restrict__ Wa,
                                          const float* __restrict__ ba,
                                          float* __restrict__ etab,
                                          float* __restrict__ atab) {
  __shared__ float s_v[8 * DV_];
  const int tid = threadIdx.x, bi = blockIdx.x;
  {
    const int j = tid >> 6, c4 = tid & 63;
    const int id = bi * 8 + j;
    float4 v = make_float4(0.f, 0.f, 0.f, 0.f);
    if (id >= 1 && id < NIID) v = ((const float4*)iemb)[(size_t)id * 64 + c4];
    *(float4*)&s_v[j * DV_ + c4 * 4] = v;
  }
  __syncthreads();
  const int gate = tid >> 8, d = tid & 255;
  const float4* wr = (const float4*)((gate ? Wa : We) + d * DV_);
  float acc[8];
#pragma unroll
  for (int j = 0; j < 8; ++j) acc[j] = 0.f;
  for (int kk = 0; kk < DV_ / 4; ++kk) {
    const float4 w4 = wr[kk];
#pragma unroll
    for (int j = 0; j < 8; ++j) acc[j] += dot4(w4, *(const float4*)&s_v[j * DV_ + kk * 4]);
  }
  const float bias = gate ? ba[d] : be[d];
#pragma unroll
  for (int j = 0; j < 8; ++j) {
    const int id = bi * 8 + j;
    if (id < NIID) {
      if (gate) atab[(size_t)id * DV_ + d] = tanhf(acc[j] + bias);
      else      etab[(size_t)id * DV_ + d] = 1.f / (1.f + expf(-(acc[j] + bias)));
    }
  }
}

// ============ kS: ring-staged mask-driven recurrence, 512 x 1024 ===========
#define ROWOP(mr, wsel)                                   \
  do {                                                    \
    const float w_ = (wsel);                              \
    racc.x = fmaf(w_, mr.x, racc.x);                      \
    racc.y = fmaf(w_, mr.y, racc.y);                      \
    racc.z = fmaf(w_, mr.z, racc.z);                      \
    racc.w = fmaf(w_, mr.w, racc.w);                      \
    mr.x = fmaf(-w_, fmaf(e4.x, mr.x, -a4.x), mr.x);      \
    mr.y = fmaf(-w_, fmaf(e4.y, mr.y, -a4.y), mr.y);      \
    mr.z = fmaf(-w_, fmaf(e4.z, mr.z, -a4.z), mr.z);      \
    mr.w = fmaf(-w_, fmaf(e4.w, mr.w, -a4.w), mr.w);      \
  } while (0)

// guarded group: scalar bit test; w-row b128 read only when hot
#define GRPH(bitv, woff, A, B, C, D)                                      \
  if (nib & (bitv)) {                                                     \
    const float4 wq = *(const float4*)(wrow + (woff));                    \
    ROWOP(A, wq.x); ROWOP(B, wq.y); ROWOP(C, wq.z); ROWOP(D, wq.w);       \
  }

__global__ __launch_bounds__(1024)
__attribute__((amdgpu_waves_per_eu(4, 4))) void kS(
    const int* __restrict__ concepts, const int* __restrict__ inter,
    const float* __restrict__ Vmem, const float* __restrict__ wtab,
    const float* __restrict__ etab, const float* __restrict__ atab,
    const u16* __restrict__ hmask, h16* __restrict__ rpart) {
  __shared__ float s_w[8][DV_];            // 8 KB: ring of 8 t-rows
  __shared__ float s_e[8][DV_];            // 8 KB
  __shared__ float s_a[8][DV_];            // 8 KB
  __shared__ __align__(16) u16 s_mask[8][8];  // 128 B: hot-group masks
  __shared__ float s_racc[2][4][16][DV_];  // 128 KB: double-buffered windows
  const int tid = threadIdx.x, bx = blockIdx.x;
  const int b = bx >> 1, ch = bx & 1;
  const int lane = tid & 63, wv = tid >> 6;  // 16 waves
  const int row0 = ch * 256 + __builtin_amdgcn_readfirstlane(wv * 16);
  const int mword = ch * 4 + (wv >> 2);      // this wave's hmask u16 index
  const int mshift = (wv & 3) * 4;           // nibble position within it
  float4 m0, m1, m2, m3, m4, m5, m6, m7, m8, m9, m10, m11, m12, m13, m14, m15;
  {
    const float4* vm4 = (const float4*)Vmem + (size_t)row0 * 64 + lane;
    m0 = vm4[0 * 64];   m1 = vm4[1 * 64];   m2 = vm4[2 * 64];   m3 = vm4[3 * 64];
    m4 = vm4[4 * 64];   m5 = vm4[5 * 64];   m6 = vm4[6 * 64];   m7 = vm4[7 * 64];
    m8 = vm4[8 * 64];   m9 = vm4[9 * 64];   m10 = vm4[10 * 64]; m11 = vm4[11 * 64];
    m12 = vm4[12 * 64]; m13 = vm4[13 * 64]; m14 = vm4[14 * 64]; m15 = vm4[15 * 64];
  }
  const int* cb = concepts + b * T_;
  const int* ib = inter + b * T_;
  const float4* wtab4 = (const float4*)wtab;
  const float4* etab4 = (const float4*)etab;
  const float4* atab4 = (const float4*)atab;
  h16* rp = rpart + (size_t)ch * NP_ * DV_ + (size_t)b * T_ * DV_;

  // stage 4 t-rows (w/e/a + mask) into ring slots (tb..tb+3)&7; 768 threads.
  auto stage4 = [&](int tb, int toff) {
    const int idx = tid - toff;
    if (idx >= 0 && idx < 768) {
      const int r = idx / 192, q = idx % 192;
      const int arr = q >> 6, c4 = q & 63;
      const int t = tb + r, sl = t & 7;
      if (arr == 0) {
        *(float4*)&s_w[sl][c4 * 4] = wtab4[(size_t)cb[t] * 128 + ch * 64 + c4];
        if (q == 0)
          *(uint4*)&s_mask[sl][0] = *(const uint4*)(hmask + (size_t)cb[t] * 8);
      } else if (arr == 1) {
        *(float4*)&s_e[sl][c4 * 4] = etab4[(size_t)ib[t] * 64 + c4];
      } else {
        *(float4*)&s_a[sl][c4 * 4] = atab4[(size_t)ib[t] * 64 + c4];
      }
    }
  };

  stage4(0, 0);
  __syncthreads();

  for (int t0 = 0; t0 < T_; t0 += 4) {
    const int win = (t0 >> 2) & 1;
#pragma unroll 1  // CAP PRESSURE: one step's LDS reads live at a time
    for (int j = 0; j < 4; ++j) {
      const int sl = (t0 + j) & 7;
      const u32 nib =
          (__builtin_amdgcn_readfirstlane((u32)s_mask[sl][mword]) >> mshift) & 0xFu;
      float4 racc = make_float4(0.f, 0.f, 0.f, 0.f);
      if (nib) {
        const float4 e4 = *(const float4*)&s_e[sl][lane * 4];
        const float4 a4 = *(const float4*)&s_a[sl][lane * 4];
        const float* wrow = &s_w[sl][wv * 16];
        GRPH(1u, 0, m0, m1, m2, m3)
        GRPH(2u, 4, m4, m5, m6, m7)
        GRPH(4u, 8, m8, m9, m10, m11)
        GRPH(8u, 12, m12, m13, m14, m15)
      }
      *(float4*)&s_racc[win][j][wv][lane * 4] = racc;
    }
    if (t0 + 4 < T_) stage4(t0 + 4, 256);
    if (t0 > 0 && tid < 256) {
      const int j = tid >> 6, l = tid & 63;
      float4 acc = make_float4(0.f, 0.f, 0.f, 0.f);
#pragma unroll 4
      for (int w2 = 0; w2 < 16; ++w2) {
        const float4 v = *(const float4*)&s_racc[win ^ 1][j][w2][l * 4];
        acc.x += v.x; acc.y += v.y; acc.z += v.z; acc.w += v.w;
      }
      *(half4*)(rp + (size_t)(t0 - 4 + j) * DV_ + l * 4) = f2h(acc);
    }
    __syncthreads();
  }
  if (tid < 256) {
    const int buf = ((T_ - 4) >> 2) & 1;
    const int j = tid >> 6, l = tid & 63;
    float4 acc = make_float4(0.f, 0.f, 0.f, 0.f);
#pragma unroll 4
    for (int w2 = 0; w2 < 16; ++w2) {
      const float4 v = *(const float4*)&s_racc[buf][j][w2][l * 4];
      acc.x += v.x; acc.y += v.y; acc.z += v.z; acc.w += v.w;
    }
    *(half4*)(rp + (size_t)(T_ - 4 + j) * DV_ + l * 4) = f2h(acc);
  }
}

// ============ kM: MLP head, 2048 blocks x 1024 thr, lane=p (R28-exact) =====
#define MP_ 64
#define SF_ 321  // s_f dword stride (odd -> bank-conflict-free b32)
#define SH_ 65   // s_h1 dword stride (odd)
#define SR_ 17   // s_red dword stride (odd)
__global__ __launch_bounds__(1024)
__attribute__((amdgpu_waves_per_eu(4, 4))) void kM(
    const int* __restrict__ concepts, const float* __restrict__ cemb,
    const h16* __restrict__ rpart, const float* __restrict__ W1,
    const float* __restrict__ b1, const float* __restrict__ W2,
    const float* __restrict__ b2, const float* __restrict__ W3,
    const float* __restrict__ b3, float* __restrict__ out) {
  __shared__ float s_f[MP_][SF_];   // 82.2 KB: f = [r(256) | q(64)] fp32
  __shared__ float s_h1[MP_][SH_];  // 16.6 KB
  __shared__ float s_red[MP_][SR_]; // 4.4 KB
  __shared__ int s_c[MP_];
  const int tid = threadIdx.x, g = blockIdx.x;
  const int lane = tid & 63, wv = tid >> 6;  // 16 waves; lane = sample p
  if (tid < MP_) s_c[tid] = concepts[g * MP_ + tid];
  __syncthreads();
  {
    const half4* p0 = (const half4*)rpart;
    const half4* p1 = p0 + (size_t)NP_ * 64;
#pragma unroll
    for (int i = 0; i < 4; ++i) {
      const int idx = tid + i * 1024, p = idx >> 6, c4 = idx & 63;
      const size_t off = (size_t)(g * MP_ + p) * 64 + c4;
      const float4 v0 = h2f(p0[off]);
      const float4 v1 = h2f(p1[off]);
      s_f[p][c4 * 4 + 0] = v0.x + v1.x;
      s_f[p][c4 * 4 + 1] = v0.y + v1.y;
      s_f[p][c4 * 4 + 2] = v0.z + v1.z;
      s_f[p][c4 * 4 + 3] = v0.w + v1.w;
    }
    const float4* ce4 = (const float4*)cemb;
    const float4 z = make_float4(0.f, 0.f, 0.f, 0.f);
    const int p = tid >> 4, k4 = tid & 15;
    const int c = s_c[p];
    const float4 q = c ? ce4[c * 16 + k4] : z;
    s_f[p][DV_ + k4 * 4 + 0] = q.x;
    s_f[p][DV_ + k4 * 4 + 1] = q.y;
    s_f[p][DV_ + k4 * 4 + 2] = q.z;
    s_f[p][DV_ + k4 * 4 + 3] = q.w;
  }
  __syncthreads();
  // ---- layer 1: h1[p][j] = relu(b1[j] + sum_k W1[j][k] f[p][k]) ----
  {
    const int j0 = __builtin_amdgcn_readfirstlane(wv * 4);  // FORCE scalar
    const float* W1r0 = W1 + (size_t)(j0 + 0) * 320;
    const float* W1r1 = W1 + (size_t)(j0 + 1) * 320;
    const float* W1r2 = W1 + (size_t)(j0 + 2) * 320;
    const float* W1r3 = W1 + (size_t)(j0 + 3) * 320;
    float a0 = b1[j0 + 0], a1 = b1[j0 + 1], a2 = b1[j0 + 2], a3 = b1[j0 + 3];
#pragma unroll 4
    for (int k4 = 0; k4 < 80; ++k4) {
      const float4 w0 = *(const float4*)(W1r0 + k4 * 4);  // s_load (uniform)
      const float4 w1 = *(const float4*)(W1r1 + k4 * 4);
      const float4 w2 = *(const float4*)(W1r2 + k4 * 4);
      const float4 w3 = *(const float4*)(W1r3 + k4 * 4);
      const float f0 = s_f[lane][k4 * 4 + 0];  // conflict-free b32
      const float f1 = s_f[lane][k4 * 4 + 1];
      const float f2 = s_f[lane][k4 * 4 + 2];
      const float f3 = s_f[lane][k4 * 4 + 3];
      a0 = fmaf(w0.x, f0, fmaf(w0.y, f1, fmaf(w0.z, f2, fmaf(w0.w, f3, a0))));
      a1 = fmaf(w1.x, f0, fmaf(w1.y, f1, fmaf(w1.z, f2, fmaf(w1.w, f3, a1))));
      a2 = fmaf(w2.x, f0, fmaf(w2.y, f1, fmaf(w2.z, f2, fmaf(w2.w, f3, a2))));
      a3 = fmaf(w3.x, f0, fmaf(w3.y, f1, fmaf(w3.z, f2, fmaf(w3.w, f3, a3))));
    }
    s_h1[lane][j0 + 0] = fmaxf(a0, 0.f);
    s_h1[lane][j0 + 1] = fmaxf(a1, 0.f);
    s_h1[lane][j0 + 2] = fmaxf(a2, 0.f);
    s_h1[lane][j0 + 3] = fmaxf(a3, 0.f);
  }
  __syncthreads();
  // ---- layer 2 + W3 partial: wave handles j2 = 4wv..4wv+3 ----
  {
    const int j0 = __builtin_amdgcn_readfirstlane(wv * 4);  // FORCE scalar
    const float* W2r0 = W2 + (size_t)(j0 + 0) * 64;
    const float* W2r1 = W2 + (size_t)(j0 + 1) * 64;
    const float* W2r2 = W2 + (size_t)(j0 + 2) * 64;
    const float* W2r3 = W2 + (size_t)(j0 + 3) * 64;
    float a0 = b2[j0 + 0], a1 = b2[j0 + 1], a2 = b2[j0 + 2], a3 = b2[j0 + 3];
#pragma unroll 4
    for (int k4 = 0; k4 < 16; ++k4) {
      const float4 w0 = *(const float4*)(W2r0 + k4 * 4);
      const float4 w1 = *(const float4*)(W2r1 + k4 * 4);
      const float4 w2 = *(const float4*)(W2r2 + k4 * 4);
      const float4 w3 = *(const float4*)(W2r3 + k4 * 4);
      const float h0 = s_h1[lane][k4 * 4 + 0];
      const float h1v = s_h1[lane][k4 * 4 + 1];
      const float h2v = s_h1[lane][k4 * 4 + 2];
      const float h3 = s_h1[lane][k4 * 4 + 3];
      a0 = fmaf(w0.x, h0, fmaf(w0.y, h1v, fmaf(w0.z, h2v, fmaf(w0.w, h3, a0))));
      a1 = fmaf(w1.x, h0, fmaf(w1.y, h1v, fmaf(w1.z, h2v, fmaf(w1.w, h3, a1))));
      a2 = fmaf(w2.x, h0, fmaf(w2.y, h1v, fmaf(w2.z, h2v, fmaf(w2.w, h3, a2))));
      a3 = fmaf(w3.x, h0, fmaf(w3.y, h1v, fmaf(w3.z, h2v, fmaf(w3.w, h3, a3))));
    }
    const float p3 = fmaxf(a0, 0.f) * W3[j0 + 0] + fmaxf(a1, 0.f) * W3[j0 + 1] +
                     fmaxf(a2, 0.f) * W3[j0 + 2] + fmaxf(a3, 0.f) * W3[j0 + 3];
    s_red[lane][wv] = p3;
  }
  __syncthreads();
  if (wv == 0) {
    float s = b3[0];
#pragma unroll
    for (int w = 0; w < 16; ++w) s += s_red[lane][w];
    out[g * MP_ + lane] = 1.f / (1.f + expf(-s));
  }
}

extern "C" void kernel_launch(void* const* d_in, const int* in_sizes, int n_in,
                              void* d_out, int out_size, void* d_ws, size_t ws_size,
                              hipStream_t stream) {
  const int* concepts = (const int*)d_in[0];
  const int* interactions = (const int*)d_in[1];
  const float* Kmem = (const float*)d_in[2];
  const float* Vmem = (const float*)d_in[3];
  const float* cemb = (const float*)d_in[4];
  const float* iemb = (const float*)d_in[5];
  const float* We = (const float*)d_in[6];
  const float* be = (const float*)d_in[7];
  const float* Wa = (const float*)d_in[8];
  const float* ba = (const float*)d_in[9];
  const float* W1 = (const float*)d_in[10];
  const float* b1 = (const float*)d_in[11];
  const float* W2 = (const float*)d_in[12];
  const float* b2 = (const float*)d_in[13];
  const float* W3 = (const float*)d_in[14];
  const float* b3 = (const float*)d_in[15];
  float* out = (float*)d_out;

  const size_t sz_w = (size_t)NCID * N_ * 4;
  const size_t sz_e = (size_t)NIID * DV_ * 4;
  float* wtab = (float*)d_ws;
  float* etab = (float*)((char*)d_ws + sz_w);
  float* atab = (float*)((char*)d_ws + sz_w + sz_e);
  u16* hmask = (u16*)((char*)d_ws + sz_w + 2 * sz_e);            // 8.2 KB
  h16* rpart = (h16*)((char*)d_ws + sz_w + 2 * sz_e + 16384);    // 2 x 64 MiB

  kW<<<dim3(NCID), dim3(512), 0, stream>>>(Kmem, cemb, wtab, hmask);
  kG<<<dim3((NIID + 7) / 8), dim3(512), 0, stream>>>(iemb, We, be, Wa, ba, etab, atab);
  kS<<<dim3(B_ * 2), dim3(1024), 0, stream>>>(concepts, interactions, Vmem,
                                              wtab, etab, atab, hmask, rpart);
  kM<<<dim3(NP_ / MP_), dim3(1024), 0, stream>>>(concepts, cemb, rpart,
                                                 W1, b1, W2, b2, W3, b3, out);
}